// Round 1
// baseline (1086.047 us; speedup 1.0000x reference)
//
#include <hip/hip_runtime.h>
#include <cmath>

#define DEV static __device__ __forceinline__

DEV float warp64_sum(float v) {
    for (int o = 32; o > 0; o >>= 1) v += __shfl_xor(v, o, 64);
    return v;
}

DEV unsigned fkey(float f) {
    unsigned b = __float_as_uint(f);
    return (b & 0x80000000u) ? ~b : (b | 0x80000000u);
}
DEV float fdecode(unsigned k) {
    return (k & 0x80000000u) ? __uint_as_float(k ^ 0x80000000u) : __uint_as_float(~k);
}

// ---------------- edge_attr mean ----------------
__global__ __launch_bounds__(256) void k_easum(const float* __restrict__ ea,
                                               float* __restrict__ sum, int E) {
    __shared__ float ls[4];
    float s = 0.f;
    for (int i = blockIdx.x * blockDim.x + threadIdx.x; i < E; i += gridDim.x * blockDim.x)
        s += ea[i];
    s = warp64_sum(s);
    int lane = threadIdx.x & 63, w = threadIdx.x >> 6;
    if (lane == 0) ls[w] = s;
    __syncthreads();
    if (threadIdx.x == 0) atomicAdd(sum, ls[0] + ls[1] + ls[2] + ls[3]);
}

// ---------------- CSR build ----------------
__global__ void k_count(const int* __restrict__ ei, int* __restrict__ cnt, int E, int Nn) {
    int total = E + Nn;
    for (int i = blockIdx.x * blockDim.x + threadIdx.x; i < total; i += gridDim.x * blockDim.x) {
        int d = (i < E) ? ei[E + i] : (i - E);
        atomicAdd(&cnt[d], 1);
    }
}

__global__ __launch_bounds__(1024) void k_scan(const int* __restrict__ counts,
                                               int* __restrict__ offs, int n) {
    __shared__ int sdata[1024];
    int t = threadIdx.x;
    int chunk = (n + 1023) / 1024;
    int b = t * chunk, e = min(b + chunk, n);
    int s = 0;
    for (int i = b; i < e; ++i) s += counts[i];
    sdata[t] = s;
    __syncthreads();
    for (int o = 1; o < 1024; o <<= 1) {
        int u = (t >= o) ? sdata[t - o] : 0;
        __syncthreads();
        sdata[t] += u;
        __syncthreads();
    }
    int run = (t > 0) ? sdata[t - 1] : 0;
    for (int i = b; i < e; ++i) { offs[i] = run; run += counts[i]; }
    if (t == 1023) offs[n] = run;
}

__global__ void k_scatter(const int* __restrict__ ei, const float* __restrict__ ea,
                          const float* __restrict__ easum, const int* __restrict__ offs,
                          int* __restrict__ cur, int* __restrict__ csrc,
                          float* __restrict__ cea, int E, int Nn) {
    float eam = easum[0] / (float)E;
    int total = E + Nn;
    for (int i = blockIdx.x * blockDim.x + threadIdx.x; i < total; i += gridDim.x * blockDim.x) {
        int s, d; float v;
        if (i < E) { s = ei[i]; d = ei[E + i]; v = ea[i]; }
        else       { s = d = i - E; v = eam; }
        int pos = offs[d] + atomicAdd(&cur[d], 1);
        csrc[pos] = s;
        cea[pos] = v;
    }
}

// ---------------- edge coefficient: coef[l][h] = sum_c We[h*64+c]*ae[h*64+c] ----------------
__global__ __launch_bounds__(256) void k_coef(const float* __restrict__ we0, const float* __restrict__ ae0,
                                              const float* __restrict__ we1, const float* __restrict__ ae1,
                                              const float* __restrict__ we2, const float* __restrict__ ae2,
                                              float* __restrict__ coef) {
    int t = threadIdx.x, h = t >> 6, lane = t & 63;
    const float* we[3] = {we0, we1, we2};
    const float* ae[3] = {ae0, ae1, ae2};
#pragma unroll
    for (int l = 0; l < 3; ++l) {
        float p = we[l][t] * ae[l][t];
        p = warp64_sum(p);
        if (lane == 0) coef[l * 4 + h] = p;
    }
}

// ---------------- GEMM: Out[N,256] = A[N,K] @ W[K,256], fp32 ----------------
__global__ __launch_bounds__(256) void k_gemm(const float* __restrict__ A,
                                              const float* __restrict__ W,
                                              float* __restrict__ Out, int nrows, int K) {
    __shared__ float Wt[32][256];
    __shared__ float Xt[32][34];   // transposed x tile, padded (2-way bank conflict on store = free)
    const int tid = threadIdx.x;
    const int lane = tid & 63, w = tid >> 6;
    const int row0 = blockIdx.x * 32;
    float acc[8][4] = {};
    for (int kk = 0; kk < K; kk += 32) {
        for (int i = tid; i < 32 * 256; i += 256)
            Wt[0][i] = W[(size_t)kk * 256 + i];
        {
            int r = tid >> 5, k2 = tid & 31;
            for (int rr = r; rr < 32; rr += 8) {
                int grow = row0 + rr;
                Xt[k2][rr] = (grow < nrows) ? A[(size_t)grow * K + kk + k2] : 0.f;
            }
        }
        __syncthreads();
#pragma unroll
        for (int k2 = 0; k2 < 32; ++k2) {
            float wv[4];
            *(float4*)wv = *(const float4*)&Wt[k2][lane * 4];
            float xs[8];
#pragma unroll
            for (int j = 0; j < 4; ++j)
                *(float2*)&xs[2 * j] = *(const float2*)&Xt[k2][w * 8 + 2 * j];
#pragma unroll
            for (int r = 0; r < 8; ++r) {
                float xv = xs[r];
#pragma unroll
                for (int j = 0; j < 4; ++j) acc[r][j] = fmaf(xv, wv[j], acc[r][j]);
            }
        }
        __syncthreads();
    }
#pragma unroll
    for (int r = 0; r < 8; ++r) {
        int grow = row0 + w * 8 + r;
        if (grow < nrows) *(float4*)&Out[(size_t)grow * 256 + lane * 4] = *(float4*)acc[r];
    }
}

// ---------------- attention scalars: s_src[n,h], s_dst[n,h] ----------------
__global__ __launch_bounds__(256) void k_s(const float* __restrict__ hlin,
                                           const float* __restrict__ as_,
                                           const float* __restrict__ ad_,
                                           float* __restrict__ ssrc, float* __restrict__ sdst) {
    int n = blockIdx.x, tid = threadIdx.x;
    float v = hlin[(size_t)n * 256 + tid];
    float ps = warp64_sum(v * as_[tid]);
    float pd = warp64_sum(v * ad_[tid]);
    if ((tid & 63) == 0) {
        int h = tid >> 6;
        ssrc[n * 4 + h] = ps;
        sdst[n * 4 + h] = pd;
    }
}

// ---------------- fused online-softmax aggregation + bias + BN (+ELU / head-mean) ----------------
template <bool MEAN>
__global__ __launch_bounds__(256) void k_agg(const float* __restrict__ hlin,
                                             const int* __restrict__ offs,
                                             const int* __restrict__ csrc,
                                             const float* __restrict__ cea,
                                             const float* __restrict__ ssrc,
                                             const float* __restrict__ sdst,
                                             const float* __restrict__ coef,
                                             const float* __restrict__ bias,
                                             const float* __restrict__ bng,
                                             const float* __restrict__ bnb,
                                             const float* __restrict__ bnm,
                                             const float* __restrict__ bnv,
                                             float* __restrict__ out) {
    __shared__ float sm[4][64];
    int n = blockIdx.x, tid = threadIdx.x;
    int h = tid >> 6;
    int b = offs[n], e = offs[n + 1];
    float sd = sdst[n * 4 + h], cf = coef[h];
    float m = -INFINITY, den = 0.f, acc = 0.f;
    for (int i = b; i < e; ++i) {
        int sn = csrc[i];
        float a = ssrc[sn * 4 + h] + sd + cf * cea[i];
        a = a > 0.f ? a : 0.2f * a;                       // leaky_relu 0.2
        float mn = fmaxf(m, a);
        float sc = __expf(m - mn);                        // 0 on first iter (m=-inf)
        float p = __expf(a - mn);
        den = den * sc + p;
        acc = acc * sc + p * hlin[(size_t)sn * 256 + tid];
        m = mn;
    }
    float res = acc / den;
    if (!MEAN) {
        float v = res + bias[tid];
        v = (v - bnm[tid]) * rsqrtf(bnv[tid] + 1e-5f) * bng[tid] + bnb[tid];
        v = v > 0.f ? v : expm1f(v);                      // ELU
        out[(size_t)n * 256 + tid] = v;
    } else {
        int c = tid & 63;
        sm[h][c] = res;
        __syncthreads();
        if (tid < 64) {
            float v = 0.25f * (sm[0][tid] + sm[1][tid] + sm[2][tid] + sm[3][tid]) + bias[tid];
            v = (v - bnm[tid]) * rsqrtf(bnv[tid] + 1e-5f) * bng[tid] + bnb[tid];
            out[(size_t)n * 64 + tid] = v;                // no ELU on layer 2
        }
    }
}

// ---------------- graph pooling ----------------
__global__ __launch_bounds__(256) void k_pool(const float* __restrict__ h2,
                                              const int* __restrict__ batch,
                                              float* __restrict__ psum,
                                              unsigned* __restrict__ pmaxk,
                                              float* __restrict__ pcnt, int Nn) {
    int idx = blockIdx.x * 4 + (threadIdx.x >> 6);
    int c = threadIdx.x & 63;
    if (idx >= Nn) return;
    int g = batch[idx];
    float v = h2[(size_t)idx * 64 + c];
    atomicAdd(&psum[g * 64 + c], v);
    atomicMax(&pmaxk[g * 64 + c], fkey(v));
    if (c == 0) atomicAdd(&pcnt[g], 1.f);
}

// ---------------- MLP head ----------------
__global__ __launch_bounds__(128) void k_mlp(const float* __restrict__ psum,
                                             const unsigned* __restrict__ pmaxk,
                                             const float* __restrict__ pcnt,
                                             const float* __restrict__ emb,
                                             const int* __restrict__ cids,
                                             const float* __restrict__ mw1, const float* __restrict__ mb1,
                                             const float* __restrict__ mw2, const float* __restrict__ mb2,
                                             const float* __restrict__ mw3, const float* __restrict__ mb3,
                                             float* __restrict__ out) {
    __shared__ float comb[144];
    __shared__ float z1[128];
    __shared__ float z2[64];
    int g = blockIdx.x, t = threadIdx.x;
    float cnt = fmaxf(pcnt[g], 1.f);
    if (t < 64) {
        comb[t] = psum[g * 64 + t] / cnt;
        comb[64 + t] = fdecode(pmaxk[g * 64 + t]);
    }
    if (t < 16) comb[128 + t] = emb[cids[g] * 16 + t];
    __syncthreads();
    float a = mb1[t];
    for (int k = 0; k < 144; ++k) a = fmaf(comb[k], mw1[k * 128 + t], a);
    z1[t] = fmaxf(a, 0.f);
    __syncthreads();
    if (t < 64) {
        float a2 = mb2[t];
        for (int k = 0; k < 128; ++k) a2 = fmaf(z1[k], mw2[k * 64 + t], a2);
        z2[t] = fmaxf(a2, 0.f);
    }
    __syncthreads();
    if (t < 2) {
        float a3 = mb3[t];
        for (int k = 0; k < 64; ++k) a3 = fmaf(z2[k], mw3[k * 2 + t], a3);
        out[g * 2 + t] = a3;
    }
}

extern "C" void kernel_launch(void* const* d_in, const int* in_sizes, int n_in,
                              void* d_out, int out_size, void* d_ws, size_t ws_size,
                              hipStream_t stream) {
    const float* x         = (const float*)d_in[0];
    const float* edge_attr = (const float*)d_in[1];
    const float* w0  = (const float*)d_in[2];
    const float* as0 = (const float*)d_in[3];
    const float* ad0 = (const float*)d_in[4];
    const float* we0 = (const float*)d_in[5];
    const float* ae0 = (const float*)d_in[6];
    const float* w1  = (const float*)d_in[7];
    const float* as1 = (const float*)d_in[8];
    const float* ad1 = (const float*)d_in[9];
    const float* we1 = (const float*)d_in[10];
    const float* ae1 = (const float*)d_in[11];
    const float* w2  = (const float*)d_in[12];
    const float* as2 = (const float*)d_in[13];
    const float* ad2 = (const float*)d_in[14];
    const float* we2 = (const float*)d_in[15];
    const float* ae2 = (const float*)d_in[16];
    const float* b0  = (const float*)d_in[17];
    const float* b1  = (const float*)d_in[18];
    const float* b2  = (const float*)d_in[19];
    const float* bn_g0 = (const float*)d_in[20];
    const float* bn_b0 = (const float*)d_in[21];
    const float* bn_m0 = (const float*)d_in[22];
    const float* bn_v0 = (const float*)d_in[23];
    const float* bn_g1 = (const float*)d_in[24];
    const float* bn_b1 = (const float*)d_in[25];
    const float* bn_m1 = (const float*)d_in[26];
    const float* bn_v1 = (const float*)d_in[27];
    const float* bn_g2 = (const float*)d_in[28];
    const float* bn_b2 = (const float*)d_in[29];
    const float* bn_m2 = (const float*)d_in[30];
    const float* bn_v2 = (const float*)d_in[31];
    const float* emb = (const float*)d_in[32];
    const float* mw1 = (const float*)d_in[33];
    const float* mb1 = (const float*)d_in[34];
    const float* mw2 = (const float*)d_in[35];
    const float* mb2 = (const float*)d_in[36];
    const float* mw3 = (const float*)d_in[37];
    const float* mb3 = (const float*)d_in[38];
    const int* edge_index = (const int*)d_in[39];
    const int* batch      = (const int*)d_in[40];
    const int* cids       = (const int*)d_in[41];

    const int N = in_sizes[40];       // 50000
    const int E = in_sizes[1];        // 300000
    const int G = in_sizes[41];       // 128
    const int EP = E + N;

    // ---- workspace layout ----
    size_t off = 0;
    auto alloc = [&](size_t bytes) -> void* {
        void* p = (char*)d_ws + off;
        off += (bytes + 255) & ~(size_t)255;
        return p;
    };
    // zero-init prefix
    int*      counts = (int*)alloc((size_t)N * 4);
    int*      cursor = (int*)alloc((size_t)N * 4);
    float*    psum   = (float*)alloc((size_t)G * 64 * 4);
    unsigned* pmaxk  = (unsigned*)alloc((size_t)G * 64 * 4);
    float*    pcnt   = (float*)alloc((size_t)G * 4);
    float*    easum  = (float*)alloc(4);
    size_t zbytes = off;
    // rest
    int*   offs = (int*)alloc((size_t)(N + 1) * 4);
    int*   csrc = (int*)alloc((size_t)EP * 4);
    float* cea  = (float*)alloc((size_t)EP * 4);
    float* ssrc = (float*)alloc((size_t)N * 4 * 4);
    float* sdst = (float*)alloc((size_t)N * 4 * 4);
    float* coef = (float*)alloc(12 * 4);
    float* hA = (float*)alloc((size_t)N * 256 * 4);
    float* hB = (float*)alloc((size_t)N * 256 * 4);
    (void)ws_size; (void)n_in; (void)out_size;

    hipMemsetAsync(d_ws, 0, zbytes, stream);

    // ---- graph preprocessing ----
    k_easum<<<512, 256, 0, stream>>>(edge_attr, easum, E);
    k_count<<<1024, 256, 0, stream>>>(edge_index, counts, E, N);
    k_scan<<<1, 1024, 0, stream>>>(counts, offs, N);
    k_scatter<<<1024, 256, 0, stream>>>(edge_index, edge_attr, easum, offs, cursor, csrc, cea, E, N);
    k_coef<<<1, 256, 0, stream>>>(we0, ae0, we1, ae1, we2, ae2, coef);

    int gemm_grid = (N + 31) / 32;

    // ---- layer 0 ----
    k_gemm<<<gemm_grid, 256, 0, stream>>>(x, w0, hA, N, 32);
    k_s<<<N, 256, 0, stream>>>(hA, as0, ad0, ssrc, sdst);
    k_agg<false><<<N, 256, 0, stream>>>(hA, offs, csrc, cea, ssrc, sdst, coef + 0,
                                        b0, bn_g0, bn_b0, bn_m0, bn_v0, hB);
    // ---- layer 1 ----
    k_gemm<<<gemm_grid, 256, 0, stream>>>(hB, w1, hA, N, 256);
    k_s<<<N, 256, 0, stream>>>(hA, as1, ad1, ssrc, sdst);
    k_agg<false><<<N, 256, 0, stream>>>(hA, offs, csrc, cea, ssrc, sdst, coef + 4,
                                        b1, bn_g1, bn_b1, bn_m1, bn_v1, hB);
    // ---- layer 2 ----
    k_gemm<<<gemm_grid, 256, 0, stream>>>(hB, w2, hA, N, 256);
    k_s<<<N, 256, 0, stream>>>(hA, as2, ad2, ssrc, sdst);
    k_agg<true><<<N, 256, 0, stream>>>(hA, offs, csrc, cea, ssrc, sdst, coef + 8,
                                       b2, bn_g2, bn_b2, bn_m2, bn_v2, hB);

    // ---- pooling + MLP head ----
    k_pool<<<(N + 3) / 4, 256, 0, stream>>>(hB, batch, psum, pmaxk, pcnt, N);
    k_mlp<<<G, 128, 0, stream>>>(psum, pmaxk, pcnt, emb, cids,
                                 mw1, mb1, mw2, mb2, mw3, mb3, (float*)d_out);
}

// Round 2
// 782.698 us; speedup vs baseline: 1.3876x; 1.3876x over previous
//
#include <hip/hip_runtime.h>
#include <cmath>

#define DEV static __device__ __forceinline__

DEV float warp64_sum(float v) {
    for (int o = 32; o > 0; o >>= 1) v += __shfl_xor(v, o, 64);
    return v;
}

DEV unsigned fkey(float f) {
    unsigned b = __float_as_uint(f);
    return (b & 0x80000000u) ? ~b : (b | 0x80000000u);
}
DEV float fdecode(unsigned k) {
    return (k & 0x80000000u) ? __uint_as_float(k ^ 0x80000000u) : __uint_as_float(~k);
}

// ---------------- edge_attr mean ----------------
__global__ __launch_bounds__(256) void k_easum(const float* __restrict__ ea,
                                               float* __restrict__ sum, int E) {
    __shared__ float ls[4];
    float s = 0.f;
    for (int i = blockIdx.x * blockDim.x + threadIdx.x; i < E; i += gridDim.x * blockDim.x)
        s += ea[i];
    s = warp64_sum(s);
    int lane = threadIdx.x & 63, w = threadIdx.x >> 6;
    if (lane == 0) ls[w] = s;
    __syncthreads();
    if (threadIdx.x == 0) atomicAdd(sum, ls[0] + ls[1] + ls[2] + ls[3]);
}

// ---------------- CSR build ----------------
__global__ void k_count(const int* __restrict__ ei, int* __restrict__ cnt, int E, int Nn) {
    int total = E + Nn;
    for (int i = blockIdx.x * blockDim.x + threadIdx.x; i < total; i += gridDim.x * blockDim.x) {
        int d = (i < E) ? ei[E + i] : (i - E);
        atomicAdd(&cnt[d], 1);
    }
}

__global__ __launch_bounds__(1024) void k_scan(const int* __restrict__ counts,
                                               int* __restrict__ offs, int n) {
    __shared__ int sdata[1024];
    int t = threadIdx.x;
    int chunk = (n + 1023) / 1024;
    int b = t * chunk, e = min(b + chunk, n);
    int s = 0;
    for (int i = b; i < e; ++i) s += counts[i];
    sdata[t] = s;
    __syncthreads();
    for (int o = 1; o < 1024; o <<= 1) {
        int u = (t >= o) ? sdata[t - o] : 0;
        __syncthreads();
        sdata[t] += u;
        __syncthreads();
    }
    int run = (t > 0) ? sdata[t - 1] : 0;
    for (int i = b; i < e; ++i) { offs[i] = run; run += counts[i]; }
    if (t == 1023) offs[n] = run;
}

__global__ void k_scatter(const int* __restrict__ ei, const float* __restrict__ ea,
                          const float* __restrict__ easum, const int* __restrict__ offs,
                          int* __restrict__ cur, int* __restrict__ csrc,
                          float* __restrict__ cea, int E, int Nn) {
    float eam = easum[0] / (float)E;
    int total = E + Nn;
    for (int i = blockIdx.x * blockDim.x + threadIdx.x; i < total; i += gridDim.x * blockDim.x) {
        int s, d; float v;
        if (i < E) { s = ei[i]; d = ei[E + i]; v = ea[i]; }
        else       { s = d = i - E; v = eam; }
        int pos = offs[d] + atomicAdd(&cur[d], 1);
        csrc[pos] = s;
        cea[pos] = v;
    }
}

// ---------------- edge coefficient: coef[l][h] = sum_c We[h*64+c]*ae[h*64+c] ----------------
__global__ __launch_bounds__(256) void k_coef(const float* __restrict__ we0, const float* __restrict__ ae0,
                                              const float* __restrict__ we1, const float* __restrict__ ae1,
                                              const float* __restrict__ we2, const float* __restrict__ ae2,
                                              float* __restrict__ coef) {
    int t = threadIdx.x, h = t >> 6, lane = t & 63;
    const float* we[3] = {we0, we1, we2};
    const float* ae[3] = {ae0, ae1, ae2};
#pragma unroll
    for (int l = 0; l < 3; ++l) {
        float p = we[l][t] * ae[l][t];
        p = warp64_sum(p);
        if (lane == 0) coef[l * 4 + h] = p;
    }
}

// ---------------- GEMM: Out[N,256] = A[N,K] @ W[K,256], fp32
//  + fused attention scalars ssrc/sdst (16-lane-group reductions over acc) ----------------
__global__ __launch_bounds__(256) void k_gemm(const float* __restrict__ A,
                                              const float* __restrict__ W,
                                              float* __restrict__ Out, int nrows, int K,
                                              const float* __restrict__ as_,
                                              const float* __restrict__ ad_,
                                              float* __restrict__ ssrc,
                                              float* __restrict__ sdst) {
    __shared__ float Wt[32][256];
    __shared__ float Xt[32][34];   // transposed x tile, padded
    const int tid = threadIdx.x;
    const int lane = tid & 63, w = tid >> 6;
    const int row0 = blockIdx.x * 32;
    float acc[8][4] = {};
    for (int kk = 0; kk < K; kk += 32) {
        for (int i = tid; i < 32 * 256; i += 256)
            Wt[0][i] = W[(size_t)kk * 256 + i];
        {
            int r = tid >> 5, k2 = tid & 31;
            for (int rr = r; rr < 32; rr += 8) {
                int grow = row0 + rr;
                Xt[k2][rr] = (grow < nrows) ? A[(size_t)grow * K + kk + k2] : 0.f;
            }
        }
        __syncthreads();
#pragma unroll
        for (int k2 = 0; k2 < 32; ++k2) {
            float wv[4];
            *(float4*)wv = *(const float4*)&Wt[k2][lane * 4];
            float xs[8];
#pragma unroll
            for (int j = 0; j < 4; ++j)
                *(float2*)&xs[2 * j] = *(const float2*)&Xt[k2][w * 8 + 2 * j];
#pragma unroll
            for (int r = 0; r < 8; ++r) {
                float xv = xs[r];
#pragma unroll
                for (int j = 0; j < 4; ++j) acc[r][j] = fmaf(xv, wv[j], acc[r][j]);
            }
        }
        __syncthreads();
    }
    float asv[4], adv[4];
    *(float4*)asv = *(const float4*)&as_[lane * 4];
    *(float4*)adv = *(const float4*)&ad_[lane * 4];
#pragma unroll
    for (int r = 0; r < 8; ++r) {
        int grow = row0 + w * 8 + r;
        float ps = 0.f, pd = 0.f;
#pragma unroll
        for (int j = 0; j < 4; ++j) { ps += acc[r][j] * asv[j]; pd += acc[r][j] * adv[j]; }
#pragma unroll
        for (int o = 1; o < 16; o <<= 1) { ps += __shfl_xor(ps, o, 64); pd += __shfl_xor(pd, o, 64); }
        if (grow < nrows) {
            *(float4*)&Out[(size_t)grow * 256 + lane * 4] = *(float4*)acc[r];
            if ((lane & 15) == 0) {
                int h = lane >> 4;
                ssrc[grow * 4 + h] = ps;
                sdst[grow * 4 + h] = pd;
            }
        }
    }
}

// ---------------- fused online-softmax aggregation + bias + BN (+ELU / head-mean) ----------------
template <bool MEAN>
__global__ __launch_bounds__(256) void k_agg(const float* __restrict__ hlin,
                                             const int* __restrict__ offs,
                                             const int* __restrict__ csrc,
                                             const float* __restrict__ cea,
                                             const float* __restrict__ ssrc,
                                             const float* __restrict__ sdst,
                                             const float* __restrict__ coef,
                                             const float* __restrict__ bias,
                                             const float* __restrict__ bng,
                                             const float* __restrict__ bnb,
                                             const float* __restrict__ bnm,
                                             const float* __restrict__ bnv,
                                             float* __restrict__ out) {
    __shared__ float sm[4][64];
    int n = blockIdx.x, tid = threadIdx.x;
    int h = tid >> 6;
    int b = offs[n], e = offs[n + 1];
    float sd = sdst[n * 4 + h], cf = coef[h];
    float m = -INFINITY, den = 0.f, acc = 0.f;
    for (int i = b; i < e; ++i) {
        int sn = csrc[i];
        float a = ssrc[sn * 4 + h] + sd + cf * cea[i];
        a = a > 0.f ? a : 0.2f * a;                       // leaky_relu 0.2
        float mn = fmaxf(m, a);
        float sc = __expf(m - mn);                        // 0 on first iter (m=-inf)
        float p = __expf(a - mn);
        den = den * sc + p;
        acc = acc * sc + p * hlin[(size_t)sn * 256 + tid];
        m = mn;
    }
    float res = acc / den;
    if (!MEAN) {
        float v = res + bias[tid];
        v = (v - bnm[tid]) * rsqrtf(bnv[tid] + 1e-5f) * bng[tid] + bnb[tid];
        v = v > 0.f ? v : expm1f(v);                      // ELU
        out[(size_t)n * 256 + tid] = v;
    } else {
        int c = tid & 63;
        sm[h][c] = res;
        __syncthreads();
        if (tid < 64) {
            float v = 0.25f * (sm[0][tid] + sm[1][tid] + sm[2][tid] + sm[3][tid]) + bias[tid];
            v = (v - bnm[tid]) * rsqrtf(bnv[tid] + 1e-5f) * bng[tid] + bnb[tid];
            out[(size_t)n * 64 + tid] = v;                // no ELU on layer 2
        }
    }
}

// ---------------- graph pooling: segmented (batch is sorted) ----------------
__global__ __launch_bounds__(256) void k_pool(const float* __restrict__ h2,
                                              const int* __restrict__ batch,
                                              float* __restrict__ psum,
                                              unsigned* __restrict__ pmaxk,
                                              float* __restrict__ pcnt, int Nn) {
    int wglob = blockIdx.x * 4 + (threadIdx.x >> 6);
    int lane = threadIdx.x & 63;
    int nwaves = gridDim.x * 4;
    int span = (Nn + nwaves - 1) / nwaves;
    int b = wglob * span, e = min(b + span, Nn);
    if (b >= e) return;
    int curg = batch[b];
    float s = 0.f, mx = -INFINITY;
    float cnt = 0.f;
    for (int i = b; i < e; ++i) {
        int g = batch[i];                       // wave-uniform broadcast
        float v = h2[(size_t)i * 64 + lane];
        if (g != curg) {
            atomicAdd(&psum[curg * 64 + lane], s);
            atomicMax(&pmaxk[curg * 64 + lane], fkey(mx));
            if (lane == 0) atomicAdd(&pcnt[curg], cnt);
            s = 0.f; mx = -INFINITY; cnt = 0.f; curg = g;
        }
        s += v; mx = fmaxf(mx, v); cnt += 1.f;
    }
    atomicAdd(&psum[curg * 64 + lane], s);
    atomicMax(&pmaxk[curg * 64 + lane], fkey(mx));
    if (lane == 0) atomicAdd(&pcnt[curg], cnt);
}

// ---------------- MLP head ----------------
__global__ __launch_bounds__(128) void k_mlp(const float* __restrict__ psum,
                                             const unsigned* __restrict__ pmaxk,
                                             const float* __restrict__ pcnt,
                                             const float* __restrict__ emb,
                                             const int* __restrict__ cids,
                                             const float* __restrict__ mw1, const float* __restrict__ mb1,
                                             const float* __restrict__ mw2, const float* __restrict__ mb2,
                                             const float* __restrict__ mw3, const float* __restrict__ mb3,
                                             float* __restrict__ out) {
    __shared__ float comb[144];
    __shared__ float z1[128];
    __shared__ float z2[64];
    int g = blockIdx.x, t = threadIdx.x;
    float cnt = fmaxf(pcnt[g], 1.f);
    if (t < 64) {
        comb[t] = psum[g * 64 + t] / cnt;
        comb[64 + t] = fdecode(pmaxk[g * 64 + t]);
    }
    if (t < 16) comb[128 + t] = emb[cids[g] * 16 + t];
    __syncthreads();
    float a = mb1[t];
    for (int k = 0; k < 144; ++k) a = fmaf(comb[k], mw1[k * 128 + t], a);
    z1[t] = fmaxf(a, 0.f);
    __syncthreads();
    if (t < 64) {
        float a2 = mb2[t];
        for (int k = 0; k < 128; ++k) a2 = fmaf(z1[k], mw2[k * 64 + t], a2);
        z2[t] = fmaxf(a2, 0.f);
    }
    __syncthreads();
    if (t < 2) {
        float a3 = mb3[t];
        for (int k = 0; k < 64; ++k) a3 = fmaf(z2[k], mw3[k * 2 + t], a3);
        out[g * 2 + t] = a3;
    }
}

extern "C" void kernel_launch(void* const* d_in, const int* in_sizes, int n_in,
                              void* d_out, int out_size, void* d_ws, size_t ws_size,
                              hipStream_t stream) {
    const float* x         = (const float*)d_in[0];
    const float* edge_attr = (const float*)d_in[1];
    const float* w0  = (const float*)d_in[2];
    const float* as0 = (const float*)d_in[3];
    const float* ad0 = (const float*)d_in[4];
    const float* we0 = (const float*)d_in[5];
    const float* ae0 = (const float*)d_in[6];
    const float* w1  = (const float*)d_in[7];
    const float* as1 = (const float*)d_in[8];
    const float* ad1 = (const float*)d_in[9];
    const float* we1 = (const float*)d_in[10];
    const float* ae1 = (const float*)d_in[11];
    const float* w2  = (const float*)d_in[12];
    const float* as2 = (const float*)d_in[13];
    const float* ad2 = (const float*)d_in[14];
    const float* we2 = (const float*)d_in[15];
    const float* ae2 = (const float*)d_in[16];
    const float* b0  = (const float*)d_in[17];
    const float* b1  = (const float*)d_in[18];
    const float* b2  = (const float*)d_in[19];
    const float* bn_g0 = (const float*)d_in[20];
    const float* bn_b0 = (const float*)d_in[21];
    const float* bn_m0 = (const float*)d_in[22];
    const float* bn_v0 = (const float*)d_in[23];
    const float* bn_g1 = (const float*)d_in[24];
    const float* bn_b1 = (const float*)d_in[25];
    const float* bn_m1 = (const float*)d_in[26];
    const float* bn_v1 = (const float*)d_in[27];
    const float* bn_g2 = (const float*)d_in[28];
    const float* bn_b2 = (const float*)d_in[29];
    const float* bn_m2 = (const float*)d_in[30];
    const float* bn_v2 = (const float*)d_in[31];
    const float* emb = (const float*)d_in[32];
    const float* mw1 = (const float*)d_in[33];
    const float* mb1 = (const float*)d_in[34];
    const float* mw2 = (const float*)d_in[35];
    const float* mb2 = (const float*)d_in[36];
    const float* mw3 = (const float*)d_in[37];
    const float* mb3 = (const float*)d_in[38];
    const int* edge_index = (const int*)d_in[39];
    const int* batch      = (const int*)d_in[40];
    const int* cids       = (const int*)d_in[41];

    const int N = in_sizes[40];       // 50000
    const int E = in_sizes[1];        // 300000
    const int G = in_sizes[41];       // 128
    const int EP = E + N;

    // ---- workspace layout ----
    size_t off = 0;
    auto alloc = [&](size_t bytes) -> void* {
        void* p = (char*)d_ws + off;
        off += (bytes + 255) & ~(size_t)255;
        return p;
    };
    // zero-init prefix
    int*      counts = (int*)alloc((size_t)N * 4);
    int*      cursor = (int*)alloc((size_t)N * 4);
    float*    psum   = (float*)alloc((size_t)G * 64 * 4);
    unsigned* pmaxk  = (unsigned*)alloc((size_t)G * 64 * 4);
    float*    pcnt   = (float*)alloc((size_t)G * 4);
    float*    easum  = (float*)alloc(4);
    size_t zbytes = off;
    // rest
    int*   offs = (int*)alloc((size_t)(N + 1) * 4);
    int*   csrc = (int*)alloc((size_t)EP * 4);
    float* cea  = (float*)alloc((size_t)EP * 4);
    float* ssrc = (float*)alloc((size_t)N * 4 * 4);
    float* sdst = (float*)alloc((size_t)N * 4 * 4);
    float* coef = (float*)alloc(12 * 4);
    float* hA = (float*)alloc((size_t)N * 256 * 4);
    float* hB = (float*)alloc((size_t)N * 256 * 4);
    (void)ws_size; (void)n_in; (void)out_size;

    hipMemsetAsync(d_ws, 0, zbytes, stream);

    // ---- graph preprocessing ----
    k_easum<<<512, 256, 0, stream>>>(edge_attr, easum, E);
    k_count<<<1024, 256, 0, stream>>>(edge_index, counts, E, N);
    k_scan<<<1, 1024, 0, stream>>>(counts, offs, N);
    k_scatter<<<1024, 256, 0, stream>>>(edge_index, edge_attr, easum, offs, cursor, csrc, cea, E, N);
    k_coef<<<1, 256, 0, stream>>>(we0, ae0, we1, ae1, we2, ae2, coef);

    int gemm_grid = (N + 31) / 32;

    // ---- layer 0 ----
    k_gemm<<<gemm_grid, 256, 0, stream>>>(x, w0, hA, N, 32, as0, ad0, ssrc, sdst);
    k_agg<false><<<N, 256, 0, stream>>>(hA, offs, csrc, cea, ssrc, sdst, coef + 0,
                                        b0, bn_g0, bn_b0, bn_m0, bn_v0, hB);
    // ---- layer 1 ----
    k_gemm<<<gemm_grid, 256, 0, stream>>>(hB, w1, hA, N, 256, as1, ad1, ssrc, sdst);
    k_agg<false><<<N, 256, 0, stream>>>(hA, offs, csrc, cea, ssrc, sdst, coef + 4,
                                        b1, bn_g1, bn_b1, bn_m1, bn_v1, hB);
    // ---- layer 2 ----
    k_gemm<<<gemm_grid, 256, 0, stream>>>(hB, w2, hA, N, 256, as2, ad2, ssrc, sdst);
    k_agg<true><<<N, 256, 0, stream>>>(hA, offs, csrc, cea, ssrc, sdst, coef + 8,
                                       b2, bn_g2, bn_b2, bn_m2, bn_v2, hB);

    // ---- pooling + MLP head ----
    k_pool<<<512, 256, 0, stream>>>(hB, batch, psum, pmaxk, pcnt, N);
    k_mlp<<<G, 128, 0, stream>>>(psum, pmaxk, pcnt, emb, cids,
                                 mw1, mb1, mw2, mb2, mw3, mb3, (float*)d_out);
}

// Round 3
// 568.827 us; speedup vs baseline: 1.9093x; 1.3760x over previous
//
#include <hip/hip_runtime.h>
#include <cmath>

#define DEV static __device__ __forceinline__

typedef _Float16 half8 __attribute__((ext_vector_type(8)));
typedef float f32x4 __attribute__((ext_vector_type(4)));

DEV float warp64_sum(float v) {
    for (int o = 32; o > 0; o >>= 1) v += __shfl_xor(v, o, 64);
    return v;
}

DEV unsigned fkey(float f) {
    unsigned b = __float_as_uint(f);
    return (b & 0x80000000u) ? ~b : (b | 0x80000000u);
}
DEV float fdecode(unsigned k) {
    return (k & 0x80000000u) ? __uint_as_float(k ^ 0x80000000u) : __uint_as_float(~k);
}

// ---------------- edge_attr mean ----------------
__global__ __launch_bounds__(256) void k_easum(const float* __restrict__ ea,
                                               float* __restrict__ sum, int E) {
    __shared__ float ls[4];
    float s = 0.f;
    for (int i = blockIdx.x * blockDim.x + threadIdx.x; i < E; i += gridDim.x * blockDim.x)
        s += ea[i];
    s = warp64_sum(s);
    int lane = threadIdx.x & 63, w = threadIdx.x >> 6;
    if (lane == 0) ls[w] = s;
    __syncthreads();
    if (threadIdx.x == 0) atomicAdd(sum, ls[0] + ls[1] + ls[2] + ls[3]);
}

// ---------------- CSR build ----------------
__global__ void k_count(const int* __restrict__ ei, int* __restrict__ cnt, int E, int Nn) {
    int total = E + Nn;
    for (int i = blockIdx.x * blockDim.x + threadIdx.x; i < total; i += gridDim.x * blockDim.x) {
        int d = (i < E) ? ei[E + i] : (i - E);
        atomicAdd(&cnt[d], 1);
    }
}

__global__ __launch_bounds__(1024) void k_scan(const int* __restrict__ counts,
                                               int* __restrict__ offs, int n) {
    __shared__ int sdata[1024];
    int t = threadIdx.x;
    int chunk = (n + 1023) / 1024;
    int b = t * chunk, e = min(b + chunk, n);
    int s = 0;
    for (int i = b; i < e; ++i) s += counts[i];
    sdata[t] = s;
    __syncthreads();
    for (int o = 1; o < 1024; o <<= 1) {
        int u = (t >= o) ? sdata[t - o] : 0;
        __syncthreads();
        sdata[t] += u;
        __syncthreads();
    }
    int run = (t > 0) ? sdata[t - 1] : 0;
    for (int i = b; i < e; ++i) { offs[i] = run; run += counts[i]; }
    if (t == 1023) offs[n] = run;
}

__global__ void k_scatter(const int* __restrict__ ei, const float* __restrict__ ea,
                          const float* __restrict__ easum, const int* __restrict__ offs,
                          int* __restrict__ cur, int* __restrict__ csrc,
                          float* __restrict__ cea, int E, int Nn) {
    float eam = easum[0] / (float)E;
    int total = E + Nn;
    for (int i = blockIdx.x * blockDim.x + threadIdx.x; i < total; i += gridDim.x * blockDim.x) {
        int s, d; float v;
        if (i < E) { s = ei[i]; d = ei[E + i]; v = ea[i]; }
        else       { s = d = i - E; v = eam; }
        int pos = offs[d] + atomicAdd(&cur[d], 1);
        csrc[pos] = s;
        cea[pos] = v;
    }
}

// ---------------- edge coefficient ----------------
__global__ __launch_bounds__(256) void k_coef(const float* __restrict__ we0, const float* __restrict__ ae0,
                                              const float* __restrict__ we1, const float* __restrict__ ae1,
                                              const float* __restrict__ we2, const float* __restrict__ ae2,
                                              float* __restrict__ coef) {
    int t = threadIdx.x, h = t >> 6, lane = t & 63;
    const float* we[3] = {we0, we1, we2};
    const float* ae[3] = {ae0, ae1, ae2};
#pragma unroll
    for (int l = 0; l < 3; ++l) {
        float p = we[l][t] * ae[l][t];
        p = warp64_sum(p);
        if (lane == 0) coef[l * 4 + h] = p;
    }
}

// ---------------- converters: fp32 -> fp16 ----------------
__global__ __launch_bounds__(256) void k_cvt_x(const float* __restrict__ x,
                                               _Float16* __restrict__ xh,
                                               int nvalid_rows, int cols, int total) {
    int i = blockIdx.x * 256 + threadIdx.x;
    if (i >= total) return;
    int r = i / cols;
    xh[i] = (r < nvalid_rows) ? (_Float16)x[i] : (_Float16)0.f;
}

// Wt[c*K + k] = W[k*256 + c]   (transposed fp16 weights)
__global__ __launch_bounds__(256) void k_cvt_w(const float* __restrict__ W,
                                               _Float16* __restrict__ Wt,
                                               int K, int total) {
    int i = blockIdx.x * 256 + threadIdx.x;
    if (i >= total) return;
    int c = i / K, k = i - c * K;
    Wt[i] = (_Float16)W[k * 256 + c];
}

// ---------------- MFMA GEMM: Out[N,256] = A[N,K] @ W[K,256]
// A fp16 [Npad,K]; Wt fp16 [256,K] (transposed); Out fp32; fused ssrc/sdst.
// block = 256 thr (4 waves); wave wc owns head wc (cols wc*64..+64); BM=64 rows.
template <int KT>
__global__ __launch_bounds__(256) void k_gemm_mfma(const _Float16* __restrict__ A,
                                                   const _Float16* __restrict__ Wt,
                                                   float* __restrict__ Out, int nrows,
                                                   const float* __restrict__ as_,
                                                   const float* __restrict__ ad_,
                                                   float* __restrict__ ssrc,
                                                   float* __restrict__ sdst) {
    const int tid = threadIdx.x;
    const int lane = tid & 63, wc = tid >> 6;
    const int l15 = lane & 15, g = lane >> 4;
    const int row0 = blockIdx.x * 64;

    f32x4 acc[4][4] = {};   // [m-frag][n-frag]

    const _Float16* Ab = A + (size_t)(row0 + l15) * KT + g * 8;
    const _Float16* Wb = Wt + (size_t)(wc * 64 + l15) * KT + g * 8;

#pragma unroll
    for (int kk = 0; kk < KT; kk += 32) {
        half8 af[4], bf[4];
#pragma unroll
        for (int m = 0; m < 4; ++m)
            af[m] = *(const half8*)(Ab + (size_t)m * 16 * KT + kk);
#pragma unroll
        for (int f = 0; f < 4; ++f)
            bf[f] = *(const half8*)(Wb + (size_t)f * 16 * KT + kk);
#pragma unroll
        for (int m = 0; m < 4; ++m)
#pragma unroll
            for (int f = 0; f < 4; ++f)
                acc[m][f] = __builtin_amdgcn_mfma_f32_16x16x32_f16(af[m], bf[f], acc[m][f], 0, 0, 0);
    }

    // attention scalars for this wave's head (wc): per-row dot with as/ad slices
    float asv[4], adv[4];
#pragma unroll
    for (int f = 0; f < 4; ++f) {
        asv[f] = as_[wc * 64 + f * 16 + l15];
        adv[f] = ad_[wc * 64 + f * 16 + l15];
    }

#pragma unroll
    for (int m = 0; m < 4; ++m) {
        float ps[4] = {}, pd[4] = {};
#pragma unroll
        for (int f = 0; f < 4; ++f)
#pragma unroll
            for (int j = 0; j < 4; ++j) {
                ps[j] = fmaf(acc[m][f][j], asv[f], ps[j]);
                pd[j] = fmaf(acc[m][f][j], adv[f], pd[j]);
            }
#pragma unroll
        for (int o = 1; o < 16; o <<= 1)
#pragma unroll
            for (int j = 0; j < 4; ++j) {
                ps[j] += __shfl_xor(ps[j], o, 64);
                pd[j] += __shfl_xor(pd[j], o, 64);
            }
        if (l15 == 0) {
#pragma unroll
            for (int j = 0; j < 4; ++j) {
                int r = row0 + m * 16 + g * 4 + j;
                if (r < nrows) {
                    ssrc[r * 4 + wc] = ps[j];
                    sdst[r * 4 + wc] = pd[j];
                }
            }
        }
#pragma unroll
        for (int f = 0; f < 4; ++f)
#pragma unroll
            for (int j = 0; j < 4; ++j) {
                int r = row0 + m * 16 + g * 4 + j;
                if (r < nrows)
                    Out[(size_t)r * 256 + wc * 64 + f * 16 + l15] = acc[m][f][j];
            }
    }
}

// ---------------- fused online-softmax aggregation + bias + BN (+ELU / head-mean) ----------------
// !MEAN: writes fp16 (next GEMM input). MEAN: writes fp32 [N,64] for pooling.
template <bool MEAN>
__global__ __launch_bounds__(256) void k_agg(const float* __restrict__ hlin,
                                             const int* __restrict__ offs,
                                             const int* __restrict__ csrc,
                                             const float* __restrict__ cea,
                                             const float* __restrict__ ssrc,
                                             const float* __restrict__ sdst,
                                             const float* __restrict__ coef,
                                             const float* __restrict__ bias,
                                             const float* __restrict__ bng,
                                             const float* __restrict__ bnb,
                                             const float* __restrict__ bnm,
                                             const float* __restrict__ bnv,
                                             _Float16* __restrict__ outh,
                                             float* __restrict__ outf) {
    __shared__ float sm[4][64];
    int n = blockIdx.x, tid = threadIdx.x;
    int h = tid >> 6;
    int b = offs[n], e = offs[n + 1];
    float sd = sdst[n * 4 + h], cf = coef[h];
    float m = -INFINITY, den = 0.f, acc = 0.f;
    for (int i = b; i < e; ++i) {
        int sn = csrc[i];
        float a = ssrc[sn * 4 + h] + sd + cf * cea[i];
        a = a > 0.f ? a : 0.2f * a;                       // leaky_relu 0.2
        float mn = fmaxf(m, a);
        float sc = __expf(m - mn);
        float p = __expf(a - mn);
        den = den * sc + p;
        acc = acc * sc + p * hlin[(size_t)sn * 256 + tid];
        m = mn;
    }
    float res = acc / den;
    if (!MEAN) {
        float v = res + bias[tid];
        v = (v - bnm[tid]) * rsqrtf(bnv[tid] + 1e-5f) * bng[tid] + bnb[tid];
        v = v > 0.f ? v : expm1f(v);                      // ELU
        outh[(size_t)n * 256 + tid] = (_Float16)v;
    } else {
        int c = tid & 63;
        sm[h][c] = res;
        __syncthreads();
        if (tid < 64) {
            float v = 0.25f * (sm[0][tid] + sm[1][tid] + sm[2][tid] + sm[3][tid]) + bias[tid];
            v = (v - bnm[tid]) * rsqrtf(bnv[tid] + 1e-5f) * bng[tid] + bnb[tid];
            outf[(size_t)n * 64 + tid] = v;
        }
    }
}

// ---------------- graph pooling: segmented (batch is sorted) ----------------
__global__ __launch_bounds__(256) void k_pool(const float* __restrict__ h2,
                                              const int* __restrict__ batch,
                                              float* __restrict__ psum,
                                              unsigned* __restrict__ pmaxk,
                                              float* __restrict__ pcnt, int Nn) {
    int wglob = blockIdx.x * 4 + (threadIdx.x >> 6);
    int lane = threadIdx.x & 63;
    int nwaves = gridDim.x * 4;
    int span = (Nn + nwaves - 1) / nwaves;
    int b = wglob * span, e = min(b + span, Nn);
    if (b >= e) return;
    int curg = batch[b];
    float s = 0.f, mx = -INFINITY;
    float cnt = 0.f;
    for (int i = b; i < e; ++i) {
        int g = batch[i];
        float v = h2[(size_t)i * 64 + lane];
        if (g != curg) {
            atomicAdd(&psum[curg * 64 + lane], s);
            atomicMax(&pmaxk[curg * 64 + lane], fkey(mx));
            if (lane == 0) atomicAdd(&pcnt[curg], cnt);
            s = 0.f; mx = -INFINITY; cnt = 0.f; curg = g;
        }
        s += v; mx = fmaxf(mx, v); cnt += 1.f;
    }
    atomicAdd(&psum[curg * 64 + lane], s);
    atomicMax(&pmaxk[curg * 64 + lane], fkey(mx));
    if (lane == 0) atomicAdd(&pcnt[curg], cnt);
}

// ---------------- MLP head ----------------
__global__ __launch_bounds__(128) void k_mlp(const float* __restrict__ psum,
                                             const unsigned* __restrict__ pmaxk,
                                             const float* __restrict__ pcnt,
                                             const float* __restrict__ emb,
                                             const int* __restrict__ cids,
                                             const float* __restrict__ mw1, const float* __restrict__ mb1,
                                             const float* __restrict__ mw2, const float* __restrict__ mb2,
                                             const float* __restrict__ mw3, const float* __restrict__ mb3,
                                             float* __restrict__ out) {
    __shared__ float comb[144];
    __shared__ float z1[128];
    __shared__ float z2[64];
    int g = blockIdx.x, t = threadIdx.x;
    float cnt = fmaxf(pcnt[g], 1.f);
    if (t < 64) {
        comb[t] = psum[g * 64 + t] / cnt;
        comb[64 + t] = fdecode(pmaxk[g * 64 + t]);
    }
    if (t < 16) comb[128 + t] = emb[cids[g] * 16 + t];
    __syncthreads();
    float a = mb1[t];
    for (int k = 0; k < 144; ++k) a = fmaf(comb[k], mw1[k * 128 + t], a);
    z1[t] = fmaxf(a, 0.f);
    __syncthreads();
    if (t < 64) {
        float a2 = mb2[t];
        for (int k = 0; k < 128; ++k) a2 = fmaf(z1[k], mw2[k * 64 + t], a2);
        z2[t] = fmaxf(a2, 0.f);
    }
    __syncthreads();
    if (t < 2) {
        float a3 = mb3[t];
        for (int k = 0; k < 64; ++k) a3 = fmaf(z2[k], mw3[k * 2 + t], a3);
        out[g * 2 + t] = a3;
    }
}

extern "C" void kernel_launch(void* const* d_in, const int* in_sizes, int n_in,
                              void* d_out, int out_size, void* d_ws, size_t ws_size,
                              hipStream_t stream) {
    const float* x         = (const float*)d_in[0];
    const float* edge_attr = (const float*)d_in[1];
    const float* w0  = (const float*)d_in[2];
    const float* as0 = (const float*)d_in[3];
    const float* ad0 = (const float*)d_in[4];
    const float* we0 = (const float*)d_in[5];
    const float* ae0 = (const float*)d_in[6];
    const float* w1  = (const float*)d_in[7];
    const float* as1 = (const float*)d_in[8];
    const float* ad1 = (const float*)d_in[9];
    const float* we1 = (const float*)d_in[10];
    const float* ae1 = (const float*)d_in[11];
    const float* w2  = (const float*)d_in[12];
    const float* as2 = (const float*)d_in[13];
    const float* ad2 = (const float*)d_in[14];
    const float* we2 = (const float*)d_in[15];
    const float* ae2 = (const float*)d_in[16];
    const float* b0  = (const float*)d_in[17];
    const float* b1  = (const float*)d_in[18];
    const float* b2  = (const float*)d_in[19];
    const float* bn_g0 = (const float*)d_in[20];
    const float* bn_b0 = (const float*)d_in[21];
    const float* bn_m0 = (const float*)d_in[22];
    const float* bn_v0 = (const float*)d_in[23];
    const float* bn_g1 = (const float*)d_in[24];
    const float* bn_b1 = (const float*)d_in[25];
    const float* bn_m1 = (const float*)d_in[26];
    const float* bn_v1 = (const float*)d_in[27];
    const float* bn_g2 = (const float*)d_in[28];
    const float* bn_b2 = (const float*)d_in[29];
    const float* bn_m2 = (const float*)d_in[30];
    const float* bn_v2 = (const float*)d_in[31];
    const float* emb = (const float*)d_in[32];
    const float* mw1 = (const float*)d_in[33];
    const float* mb1 = (const float*)d_in[34];
    const float* mw2 = (const float*)d_in[35];
    const float* mb2 = (const float*)d_in[36];
    const float* mw3 = (const float*)d_in[37];
    const float* mb3 = (const float*)d_in[38];
    const int* edge_index = (const int*)d_in[39];
    const int* batch      = (const int*)d_in[40];
    const int* cids       = (const int*)d_in[41];

    const int N = in_sizes[40];       // 50000
    const int E = in_sizes[1];        // 300000
    const int G = in_sizes[41];       // 128
    const int EP = E + N;
    const int NB = (N + 63) / 64;     // gemm blocks
    const int Npad = NB * 64;         // padded rows

    // ---- workspace layout ----
    size_t off = 0;
    auto alloc = [&](size_t bytes) -> void* {
        void* p = (char*)d_ws + off;
        off += (bytes + 255) & ~(size_t)255;
        return p;
    };
    // zero-init prefix
    int*      counts = (int*)alloc((size_t)N * 4);
    int*      cursor = (int*)alloc((size_t)N * 4);
    float*    psum   = (float*)alloc((size_t)G * 64 * 4);
    unsigned* pmaxk  = (unsigned*)alloc((size_t)G * 64 * 4);
    float*    pcnt   = (float*)alloc((size_t)G * 4);
    float*    easum  = (float*)alloc(4);
    size_t zbytes = off;
    // rest
    int*   offs = (int*)alloc((size_t)(N + 1) * 4);
    int*   csrc = (int*)alloc((size_t)EP * 4);
    float* cea  = (float*)alloc((size_t)EP * 4);
    float* ssrc = (float*)alloc((size_t)N * 4 * 4);
    float* sdst = (float*)alloc((size_t)N * 4 * 4);
    float* coef = (float*)alloc(12 * 4);
    _Float16* xh  = (_Float16*)alloc((size_t)Npad * 32 * 2);
    _Float16* wt0 = (_Float16*)alloc((size_t)256 * 32 * 2);
    _Float16* wt1 = (_Float16*)alloc((size_t)256 * 256 * 2);
    _Float16* wt2 = (_Float16*)alloc((size_t)256 * 256 * 2);
    float*    hA  = (float*)alloc((size_t)Npad * 256 * 4);     // GEMM out (fp32)
    _Float16* hB  = (_Float16*)alloc((size_t)Npad * 256 * 2);  // agg out (fp16)
    float*    h2  = (float*)alloc((size_t)N * 64 * 4);         // layer-2 out
    (void)ws_size; (void)n_in; (void)out_size;

    hipMemsetAsync(d_ws, 0, zbytes, stream);

    // ---- graph preprocessing ----
    k_easum<<<512, 256, 0, stream>>>(edge_attr, easum, E);
    k_count<<<1024, 256, 0, stream>>>(edge_index, counts, E, N);
    k_scan<<<1, 1024, 0, stream>>>(counts, offs, N);
    k_scatter<<<1024, 256, 0, stream>>>(edge_index, edge_attr, easum, offs, cursor, csrc, cea, E, N);
    k_coef<<<1, 256, 0, stream>>>(we0, ae0, we1, ae1, we2, ae2, coef);

    // ---- fp16 conversions ----
    {
        int tot = Npad * 32;
        k_cvt_x<<<(tot + 255) / 256, 256, 0, stream>>>(x, xh, N, 32, tot);
        k_cvt_w<<<(256 * 32 + 255) / 256, 256, 0, stream>>>(w0, wt0, 32, 256 * 32);
        k_cvt_w<<<(256 * 256 + 255) / 256, 256, 0, stream>>>(w1, wt1, 256, 256 * 256);
        k_cvt_w<<<(256 * 256 + 255) / 256, 256, 0, stream>>>(w2, wt2, 256, 256 * 256);
    }

    // ---- layer 0 ----
    k_gemm_mfma<32><<<NB, 256, 0, stream>>>(xh, wt0, hA, N, as0, ad0, ssrc, sdst);
    k_agg<false><<<N, 256, 0, stream>>>(hA, offs, csrc, cea, ssrc, sdst, coef + 0,
                                        b0, bn_g0, bn_b0, bn_m0, bn_v0, hB, nullptr);
    // ---- layer 1 ----
    k_gemm_mfma<256><<<NB, 256, 0, stream>>>(hB, wt1, hA, N, as1, ad1, ssrc, sdst);
    k_agg<false><<<N, 256, 0, stream>>>(hA, offs, csrc, cea, ssrc, sdst, coef + 4,
                                        b1, bn_g1, bn_b1, bn_m1, bn_v1, hB, nullptr);
    // ---- layer 2 ----
    k_gemm_mfma<256><<<NB, 256, 0, stream>>>(hB, wt2, hA, N, as2, ad2, ssrc, sdst);
    k_agg<true><<<N, 256, 0, stream>>>(hA, offs, csrc, cea, ssrc, sdst, coef + 8,
                                       b2, bn_g2, bn_b2, bn_m2, bn_v2, nullptr, h2);

    // ---- pooling + MLP head ----
    k_pool<<<512, 256, 0, stream>>>(h2, batch, psum, pmaxk, pcnt, N);
    k_mlp<<<G, 128, 0, stream>>>(psum, pmaxk, pcnt, emb, cids,
                                 mw1, mb1, mw2, mb2, mw3, mb3, (float*)d_out);
}

// Round 4
// 423.415 us; speedup vs baseline: 2.5650x; 1.3434x over previous
//
#include <hip/hip_runtime.h>
#include <cmath>

#define DEV static __device__ __forceinline__

typedef _Float16 half8 __attribute__((ext_vector_type(8)));
typedef _Float16 half4 __attribute__((ext_vector_type(4)));
typedef float f32x4 __attribute__((ext_vector_type(4)));

DEV float warp64_sum(float v) {
    for (int o = 32; o > 0; o >>= 1) v += __shfl_xor(v, o, 64);
    return v;
}

DEV unsigned fkey(float f) {
    unsigned b = __float_as_uint(f);
    return (b & 0x80000000u) ? ~b : (b | 0x80000000u);
}
DEV float fdecode(unsigned k) {
    return (k & 0x80000000u) ? __uint_as_float(k ^ 0x80000000u) : __uint_as_float(~k);
}

// ---------------- edge_attr mean ----------------
__global__ __launch_bounds__(256) void k_easum(const float* __restrict__ ea,
                                               float* __restrict__ sum, int E) {
    __shared__ float ls[4];
    float s = 0.f;
    for (int i = blockIdx.x * blockDim.x + threadIdx.x; i < E; i += gridDim.x * blockDim.x)
        s += ea[i];
    s = warp64_sum(s);
    int lane = threadIdx.x & 63, w = threadIdx.x >> 6;
    if (lane == 0) ls[w] = s;
    __syncthreads();
    if (threadIdx.x == 0) atomicAdd(sum, ls[0] + ls[1] + ls[2] + ls[3]);
}

// ---------------- CSR build ----------------
__global__ void k_count(const int* __restrict__ ei, int* __restrict__ cnt, int E, int Nn) {
    int total = E + Nn;
    for (int i = blockIdx.x * blockDim.x + threadIdx.x; i < total; i += gridDim.x * blockDim.x) {
        int d = (i < E) ? ei[E + i] : (i - E);
        atomicAdd(&cnt[d], 1);
    }
}

__global__ __launch_bounds__(1024) void k_scan(const int* __restrict__ counts,
                                               int* __restrict__ offs, int n) {
    __shared__ int sdata[1024];
    int t = threadIdx.x;
    int chunk = (n + 1023) / 1024;
    int b = t * chunk, e = min(b + chunk, n);
    int s = 0;
    for (int i = b; i < e; ++i) s += counts[i];
    sdata[t] = s;
    __syncthreads();
    for (int o = 1; o < 1024; o <<= 1) {
        int u = (t >= o) ? sdata[t - o] : 0;
        __syncthreads();
        sdata[t] += u;
        __syncthreads();
    }
    int run = (t > 0) ? sdata[t - 1] : 0;
    for (int i = b; i < e; ++i) { offs[i] = run; run += counts[i]; }
    if (t == 1023) offs[n] = run;
}

__global__ void k_scatter(const int* __restrict__ ei, const float* __restrict__ ea,
                          const float* __restrict__ easum, const int* __restrict__ offs,
                          int* __restrict__ cur, int* __restrict__ csrc,
                          float* __restrict__ cea, int E, int Nn) {
    float eam = easum[0] / (float)E;
    int total = E + Nn;
    for (int i = blockIdx.x * blockDim.x + threadIdx.x; i < total; i += gridDim.x * blockDim.x) {
        int s, d; float v;
        if (i < E) { s = ei[i]; d = ei[E + i]; v = ea[i]; }
        else       { s = d = i - E; v = eam; }
        int pos = offs[d] + atomicAdd(&cur[d], 1);
        csrc[pos] = s;
        cea[pos] = v;
    }
}

// ---------------- edge coefficient ----------------
__global__ __launch_bounds__(256) void k_coef(const float* __restrict__ we0, const float* __restrict__ ae0,
                                              const float* __restrict__ we1, const float* __restrict__ ae1,
                                              const float* __restrict__ we2, const float* __restrict__ ae2,
                                              float* __restrict__ coef) {
    int t = threadIdx.x, h = t >> 6, lane = t & 63;
    const float* we[3] = {we0, we1, we2};
    const float* ae[3] = {ae0, ae1, ae2};
#pragma unroll
    for (int l = 0; l < 3; ++l) {
        float p = we[l][t] * ae[l][t];
        p = warp64_sum(p);
        if (lane == 0) coef[l * 4 + h] = p;
    }
}

// ---------------- converters: fp32 -> fp16 ----------------
__global__ __launch_bounds__(256) void k_cvt_x(const float* __restrict__ x,
                                               _Float16* __restrict__ xh,
                                               int nvalid_rows, int cols, int total) {
    int i = blockIdx.x * 256 + threadIdx.x;
    if (i >= total) return;
    int r = i / cols;
    xh[i] = (r < nvalid_rows) ? (_Float16)x[i] : (_Float16)0.f;
}

// Wt[c*K + k] = W[k*256 + c]   (transposed fp16 weights)
__global__ __launch_bounds__(256) void k_cvt_w(const float* __restrict__ W,
                                               _Float16* __restrict__ Wt,
                                               int K, int total) {
    int i = blockIdx.x * 256 + threadIdx.x;
    if (i >= total) return;
    int c = i / K, k = i - c * K;
    Wt[i] = (_Float16)W[k * 256 + c];
}

// ---------------- MFMA GEMM: Out[N,256] = A[N,K] @ W[K,256]
// A fp16 [Npad,K]; Wt fp16 [256,K] (transposed); Out fp16; fused fp32 ssrc/sdst.
template <int KT>
__global__ __launch_bounds__(256) void k_gemm_mfma(const _Float16* __restrict__ A,
                                                   const _Float16* __restrict__ Wt,
                                                   _Float16* __restrict__ Out, int nrows,
                                                   const float* __restrict__ as_,
                                                   const float* __restrict__ ad_,
                                                   float* __restrict__ ssrc,
                                                   float* __restrict__ sdst) {
    const int tid = threadIdx.x;
    const int lane = tid & 63, wc = tid >> 6;
    const int l15 = lane & 15, g = lane >> 4;
    const int row0 = blockIdx.x * 64;

    f32x4 acc[4][4] = {};   // [m-frag][n-frag]

    const _Float16* Ab = A + (size_t)(row0 + l15) * KT + g * 8;
    const _Float16* Wb = Wt + (size_t)(wc * 64 + l15) * KT + g * 8;

#pragma unroll
    for (int kk = 0; kk < KT; kk += 32) {
        half8 af[4], bf[4];
#pragma unroll
        for (int m = 0; m < 4; ++m)
            af[m] = *(const half8*)(Ab + (size_t)m * 16 * KT + kk);
#pragma unroll
        for (int f = 0; f < 4; ++f)
            bf[f] = *(const half8*)(Wb + (size_t)f * 16 * KT + kk);
#pragma unroll
        for (int m = 0; m < 4; ++m)
#pragma unroll
            for (int f = 0; f < 4; ++f)
                acc[m][f] = __builtin_amdgcn_mfma_f32_16x16x32_f16(af[m], bf[f], acc[m][f], 0, 0, 0);
    }

    float asv[4], adv[4];
#pragma unroll
    for (int f = 0; f < 4; ++f) {
        asv[f] = as_[wc * 64 + f * 16 + l15];
        adv[f] = ad_[wc * 64 + f * 16 + l15];
    }

#pragma unroll
    for (int m = 0; m < 4; ++m) {
        float ps[4] = {}, pd[4] = {};
#pragma unroll
        for (int f = 0; f < 4; ++f)
#pragma unroll
            for (int j = 0; j < 4; ++j) {
                ps[j] = fmaf(acc[m][f][j], asv[f], ps[j]);
                pd[j] = fmaf(acc[m][f][j], adv[f], pd[j]);
            }
#pragma unroll
        for (int o = 1; o < 16; o <<= 1)
#pragma unroll
            for (int j = 0; j < 4; ++j) {
                ps[j] += __shfl_xor(ps[j], o, 64);
                pd[j] += __shfl_xor(pd[j], o, 64);
            }
        if (l15 == 0) {
#pragma unroll
            for (int j = 0; j < 4; ++j) {
                int r = row0 + m * 16 + g * 4 + j;
                if (r < nrows) {
                    ssrc[r * 4 + wc] = ps[j];
                    sdst[r * 4 + wc] = pd[j];
                }
            }
        }
#pragma unroll
        for (int f = 0; f < 4; ++f)
#pragma unroll
            for (int j = 0; j < 4; ++j) {
                int r = row0 + m * 16 + g * 4 + j;
                if (r < nrows)
                    Out[(size_t)r * 256 + wc * 64 + f * 16 + l15] = (_Float16)acc[m][f][j];
            }
    }
}

// ---------------- fused online-softmax aggregation: ONE NODE PER WAVE ----------------
// lane handles channels [lane*4 .. lane*4+3]; head = lane>>4 (wave-local).
// hlin fp16 gather, fp32 accumulate. !MEAN: fp16 out (next GEMM input) + bias/BN/ELU.
// MEAN: head-mean via xor-shuffle, fp32 [N,64] out + bias/BN.
template <bool MEAN>
__global__ __launch_bounds__(256) void k_agg(const _Float16* __restrict__ hlin,
                                             const int* __restrict__ offs,
                                             const int* __restrict__ csrc,
                                             const float* __restrict__ cea,
                                             const float* __restrict__ ssrc,
                                             const float* __restrict__ sdst,
                                             const float* __restrict__ coef,
                                             const float* __restrict__ bias,
                                             const float* __restrict__ bng,
                                             const float* __restrict__ bnb,
                                             const float* __restrict__ bnm,
                                             const float* __restrict__ bnv,
                                             _Float16* __restrict__ outh,
                                             float* __restrict__ outf, int Nn) {
    int n = blockIdx.x * 4 + (threadIdx.x >> 6);
    if (n >= Nn) return;
    int lane = threadIdx.x & 63;
    int h = lane >> 4;
    float sd = sdst[n * 4 + h], cf = coef[h];
    int b = offs[n], e = offs[n + 1];

    float m = -INFINITY, den = 0.f;
    float acc[4] = {};

    // software pipeline: prefetch edge i+1 while computing edge i
    int sn = csrc[b];
    float ce = cea[b];
    half4 hv = *(const half4*)(hlin + (size_t)sn * 256 + lane * 4);
    float sv = ssrc[sn * 4 + h];
    for (int i = b; i < e; ++i) {
        int sn2 = 0; float ce2 = 0.f, sv2 = 0.f; half4 hv2 = {};
        if (i + 1 < e) {
            sn2 = csrc[i + 1];
            ce2 = cea[i + 1];
            hv2 = *(const half4*)(hlin + (size_t)sn2 * 256 + lane * 4);
            sv2 = ssrc[sn2 * 4 + h];
        }
        float a = sv + sd + cf * ce;
        a = a > 0.f ? a : 0.2f * a;                       // leaky_relu 0.2
        float mn = fmaxf(m, a);
        float sc = __expf(m - mn);
        float p = __expf(a - mn);
        den = den * sc + p;
#pragma unroll
        for (int j = 0; j < 4; ++j)
            acc[j] = acc[j] * sc + p * (float)hv[j];
        m = mn;
        sn = sn2; ce = ce2; hv = hv2; sv = sv2;
    }
    float inv = 1.f / den;

    if (!MEAN) {
        int c = lane * 4;
        float4 bi = *(const float4*)&bias[c];
        float4 g4 = *(const float4*)&bng[c];
        float4 b4 = *(const float4*)&bnb[c];
        float4 m4 = *(const float4*)&bnm[c];
        float4 v4 = *(const float4*)&bnv[c];
        half4 o;
#pragma unroll
        for (int j = 0; j < 4; ++j) {
            float v = acc[j] * inv + (&bi.x)[j];
            v = (v - (&m4.x)[j]) * rsqrtf((&v4.x)[j] + 1e-5f) * (&g4.x)[j] + (&b4.x)[j];
            v = v > 0.f ? v : expm1f(v);                  // ELU
            o[j] = (_Float16)v;
        }
        *(half4*)(outh + (size_t)n * 256 + c) = o;
    } else {
        float r[4];
#pragma unroll
        for (int j = 0; j < 4; ++j) {
            r[j] = acc[j] * inv;
            r[j] += __shfl_xor(r[j], 16, 64);
            r[j] += __shfl_xor(r[j], 32, 64);             // sum over 4 heads
        }
        if (lane < 16) {
            int c = lane * 4;
#pragma unroll
            for (int j = 0; j < 4; ++j) {
                float v = 0.25f * r[j] + bias[c + j];
                v = (v - bnm[c + j]) * rsqrtf(bnv[c + j] + 1e-5f) * bng[c + j] + bnb[c + j];
                outf[(size_t)n * 64 + c + j] = v;
            }
        }
    }
}

// ---------------- graph pooling: segmented (batch is sorted) ----------------
__global__ __launch_bounds__(256) void k_pool(const float* __restrict__ h2,
                                              const int* __restrict__ batch,
                                              float* __restrict__ psum,
                                              unsigned* __restrict__ pmaxk,
                                              float* __restrict__ pcnt, int Nn) {
    int wglob = blockIdx.x * 4 + (threadIdx.x >> 6);
    int lane = threadIdx.x & 63;
    int nwaves = gridDim.x * 4;
    int span = (Nn + nwaves - 1) / nwaves;
    int b = wglob * span, e = min(b + span, Nn);
    if (b >= e) return;
    int curg = batch[b];
    float s = 0.f, mx = -INFINITY;
    float cnt = 0.f;
    for (int i = b; i < e; ++i) {
        int g = batch[i];
        float v = h2[(size_t)i * 64 + lane];
        if (g != curg) {
            atomicAdd(&psum[curg * 64 + lane], s);
            atomicMax(&pmaxk[curg * 64 + lane], fkey(mx));
            if (lane == 0) atomicAdd(&pcnt[curg], cnt);
            s = 0.f; mx = -INFINITY; cnt = 0.f; curg = g;
        }
        s += v; mx = fmaxf(mx, v); cnt += 1.f;
    }
    atomicAdd(&psum[curg * 64 + lane], s);
    atomicMax(&pmaxk[curg * 64 + lane], fkey(mx));
    if (lane == 0) atomicAdd(&pcnt[curg], cnt);
}

// ---------------- MLP head ----------------
__global__ __launch_bounds__(128) void k_mlp(const float* __restrict__ psum,
                                             const unsigned* __restrict__ pmaxk,
                                             const float* __restrict__ pcnt,
                                             const float* __restrict__ emb,
                                             const int* __restrict__ cids,
                                             const float* __restrict__ mw1, const float* __restrict__ mb1,
                                             const float* __restrict__ mw2, const float* __restrict__ mb2,
                                             const float* __restrict__ mw3, const float* __restrict__ mb3,
                                             float* __restrict__ out) {
    __shared__ float comb[144];
    __shared__ float z1[128];
    __shared__ float z2[64];
    int g = blockIdx.x, t = threadIdx.x;
    float cnt = fmaxf(pcnt[g], 1.f);
    if (t < 64) {
        comb[t] = psum[g * 64 + t] / cnt;
        comb[64 + t] = fdecode(pmaxk[g * 64 + t]);
    }
    if (t < 16) comb[128 + t] = emb[cids[g] * 16 + t];
    __syncthreads();
    float a = mb1[t];
    for (int k = 0; k < 144; ++k) a = fmaf(comb[k], mw1[k * 128 + t], a);
    z1[t] = fmaxf(a, 0.f);
    __syncthreads();
    if (t < 64) {
        float a2 = mb2[t];
        for (int k = 0; k < 128; ++k) a2 = fmaf(z1[k], mw2[k * 64 + t], a2);
        z2[t] = fmaxf(a2, 0.f);
    }
    __syncthreads();
    if (t < 2) {
        float a3 = mb3[t];
        for (int k = 0; k < 64; ++k) a3 = fmaf(z2[k], mw3[k * 2 + t], a3);
        out[g * 2 + t] = a3;
    }
}

extern "C" void kernel_launch(void* const* d_in, const int* in_sizes, int n_in,
                              void* d_out, int out_size, void* d_ws, size_t ws_size,
                              hipStream_t stream) {
    const float* x         = (const float*)d_in[0];
    const float* edge_attr = (const float*)d_in[1];
    const float* w0  = (const float*)d_in[2];
    const float* as0 = (const float*)d_in[3];
    const float* ad0 = (const float*)d_in[4];
    const float* we0 = (const float*)d_in[5];
    const float* ae0 = (const float*)d_in[6];
    const float* w1  = (const float*)d_in[7];
    const float* as1 = (const float*)d_in[8];
    const float* ad1 = (const float*)d_in[9];
    const float* we1 = (const float*)d_in[10];
    const float* ae1 = (const float*)d_in[11];
    const float* w2  = (const float*)d_in[12];
    const float* as2 = (const float*)d_in[13];
    const float* ad2 = (const float*)d_in[14];
    const float* we2 = (const float*)d_in[15];
    const float* ae2 = (const float*)d_in[16];
    const float* b0  = (const float*)d_in[17];
    const float* b1  = (const float*)d_in[18];
    const float* b2  = (const float*)d_in[19];
    const float* bn_g0 = (const float*)d_in[20];
    const float* bn_b0 = (const float*)d_in[21];
    const float* bn_m0 = (const float*)d_in[22];
    const float* bn_v0 = (const float*)d_in[23];
    const float* bn_g1 = (const float*)d_in[24];
    const float* bn_b1 = (const float*)d_in[25];
    const float* bn_m1 = (const float*)d_in[26];
    const float* bn_v1 = (const float*)d_in[27];
    const float* bn_g2 = (const float*)d_in[28];
    const float* bn_b2 = (const float*)d_in[29];
    const float* bn_m2 = (const float*)d_in[30];
    const float* bn_v2 = (const float*)d_in[31];
    const float* emb = (const float*)d_in[32];
    const float* mw1 = (const float*)d_in[33];
    const float* mb1 = (const float*)d_in[34];
    const float* mw2 = (const float*)d_in[35];
    const float* mb2 = (const float*)d_in[36];
    const float* mw3 = (const float*)d_in[37];
    const float* mb3 = (const float*)d_in[38];
    const int* edge_index = (const int*)d_in[39];
    const int* batch      = (const int*)d_in[40];
    const int* cids       = (const int*)d_in[41];

    const int N = in_sizes[40];       // 50000
    const int E = in_sizes[1];        // 300000
    const int G = in_sizes[41];       // 128
    const int EP = E + N;
    const int NB = (N + 63) / 64;     // gemm blocks
    const int Npad = NB * 64;         // padded rows

    // ---- workspace layout ----
    size_t off = 0;
    auto alloc = [&](size_t bytes) -> void* {
        void* p = (char*)d_ws + off;
        off += (bytes + 255) & ~(size_t)255;
        return p;
    };
    // zero-init prefix
    int*      counts = (int*)alloc((size_t)N * 4);
    int*      cursor = (int*)alloc((size_t)N * 4);
    float*    psum   = (float*)alloc((size_t)G * 64 * 4);
    unsigned* pmaxk  = (unsigned*)alloc((size_t)G * 64 * 4);
    float*    pcnt   = (float*)alloc((size_t)G * 4);
    float*    easum  = (float*)alloc(4);
    size_t zbytes = off;
    // rest
    int*   offs = (int*)alloc((size_t)(N + 1) * 4);
    int*   csrc = (int*)alloc((size_t)EP * 4);
    float* cea  = (float*)alloc((size_t)EP * 4);
    float* ssrc = (float*)alloc((size_t)N * 4 * 4);
    float* sdst = (float*)alloc((size_t)N * 4 * 4);
    float* coef = (float*)alloc(12 * 4);
    _Float16* xh  = (_Float16*)alloc((size_t)Npad * 32 * 2);
    _Float16* wt0 = (_Float16*)alloc((size_t)256 * 32 * 2);
    _Float16* wt1 = (_Float16*)alloc((size_t)256 * 256 * 2);
    _Float16* wt2 = (_Float16*)alloc((size_t)256 * 256 * 2);
    _Float16* hH  = (_Float16*)alloc((size_t)Npad * 256 * 2);  // GEMM out (fp16, gather src)
    _Float16* hB  = (_Float16*)alloc((size_t)Npad * 256 * 2);  // agg out (fp16, GEMM in)
    float*    h2  = (float*)alloc((size_t)N * 64 * 4);         // layer-2 out
    (void)ws_size; (void)n_in; (void)out_size;

    hipMemsetAsync(d_ws, 0, zbytes, stream);

    // ---- graph preprocessing ----
    k_easum<<<512, 256, 0, stream>>>(edge_attr, easum, E);
    k_count<<<1024, 256, 0, stream>>>(edge_index, counts, E, N);
    k_scan<<<1, 1024, 0, stream>>>(counts, offs, N);
    k_scatter<<<1024, 256, 0, stream>>>(edge_index, edge_attr, easum, offs, cursor, csrc, cea, E, N);
    k_coef<<<1, 256, 0, stream>>>(we0, ae0, we1, ae1, we2, ae2, coef);

    // ---- fp16 conversions ----
    {
        int tot = Npad * 32;
        k_cvt_x<<<(tot + 255) / 256, 256, 0, stream>>>(x, xh, N, 32, tot);
        k_cvt_w<<<(256 * 32 + 255) / 256, 256, 0, stream>>>(w0, wt0, 32, 256 * 32);
        k_cvt_w<<<(256 * 256 + 255) / 256, 256, 0, stream>>>(w1, wt1, 256, 256 * 256);
        k_cvt_w<<<(256 * 256 + 255) / 256, 256, 0, stream>>>(w2, wt2, 256, 256 * 256);
    }

    int agg_grid = (N + 3) / 4;

    // ---- layer 0 ----
    k_gemm_mfma<32><<<NB, 256, 0, stream>>>(xh, wt0, hH, N, as0, ad0, ssrc, sdst);
    k_agg<false><<<agg_grid, 256, 0, stream>>>(hH, offs, csrc, cea, ssrc, sdst, coef + 0,
                                               b0, bn_g0, bn_b0, bn_m0, bn_v0, hB, nullptr, N);
    // ---- layer 1 ----
    k_gemm_mfma<256><<<NB, 256, 0, stream>>>(hB, wt1, hH, N, as1, ad1, ssrc, sdst);
    k_agg<false><<<agg_grid, 256, 0, stream>>>(hH, offs, csrc, cea, ssrc, sdst, coef + 4,
                                               b1, bn_g1, bn_b1, bn_m1, bn_v1, hB, nullptr, N);
    // ---- layer 2 ----
    k_gemm_mfma<256><<<NB, 256, 0, stream>>>(hB, wt2, hH, N, as2, ad2, ssrc, sdst);
    k_agg<true><<<agg_grid, 256, 0, stream>>>(hH, offs, csrc, cea, ssrc, sdst, coef + 8,
                                              b2, bn_g2, bn_b2, bn_m2, bn_v2, nullptr, h2, N);

    // ---- pooling + MLP head ----
    k_pool<<<512, 256, 0, stream>>>(h2, batch, psum, pmaxk, pcnt, N);
    k_mlp<<<G, 128, 0, stream>>>(psum, pmaxk, pcnt, emb, cids,
                                 mw1, mb1, mw2, mb2, mw3, mb3, (float*)d_out);
}

// Round 5
// 353.825 us; speedup vs baseline: 3.0694x; 1.1967x over previous
//
#include <hip/hip_runtime.h>
#include <cmath>

#define DEV static __device__ __forceinline__

typedef _Float16 half8 __attribute__((ext_vector_type(8)));
typedef _Float16 half4 __attribute__((ext_vector_type(4)));
typedef float f32x4 __attribute__((ext_vector_type(4)));

DEV float warp64_sum(float v) {
    for (int o = 32; o > 0; o >>= 1) v += __shfl_xor(v, o, 64);
    return v;
}

DEV unsigned fkey(float f) {
    unsigned b = __float_as_uint(f);
    return (b & 0x80000000u) ? ~b : (b | 0x80000000u);
}
DEV float fdecode(unsigned k) {
    return (k & 0x80000000u) ? __uint_as_float(k ^ 0x80000000u) : __uint_as_float(~k);
}

// ---------------- edge_attr mean ----------------
__global__ __launch_bounds__(256) void k_easum(const float* __restrict__ ea,
                                               float* __restrict__ sum, int E) {
    __shared__ float ls[4];
    float s = 0.f;
    for (int i = blockIdx.x * blockDim.x + threadIdx.x; i < E; i += gridDim.x * blockDim.x)
        s += ea[i];
    s = warp64_sum(s);
    int lane = threadIdx.x & 63, w = threadIdx.x >> 6;
    if (lane == 0) ls[w] = s;
    __syncthreads();
    if (threadIdx.x == 0) atomicAdd(sum, ls[0] + ls[1] + ls[2] + ls[3]);
}

// ---------------- CSR build ----------------
__global__ void k_count(const int* __restrict__ ei, int* __restrict__ cnt, int E, int Nn) {
    int total = E + Nn;
    for (int i = blockIdx.x * blockDim.x + threadIdx.x; i < total; i += gridDim.x * blockDim.x) {
        int d = (i < E) ? ei[E + i] : (i - E);
        atomicAdd(&cnt[d], 1);
    }
}

// ---- hierarchical exclusive scan: 1024 elems per block ----
__global__ __launch_bounds__(256) void k_scan1(const int* __restrict__ counts,
                                               int* __restrict__ offs,
                                               int* __restrict__ bsum, int n) {
    __shared__ int ls[256];
    int t = threadIdx.x;
    int base = blockIdx.x * 1024 + t * 4;
    int4 v = {0, 0, 0, 0};
    if (base + 3 < n) v = *(const int4*)&counts[base];
    else {
        if (base + 0 < n) v.x = counts[base + 0];
        if (base + 1 < n) v.y = counts[base + 1];
        if (base + 2 < n) v.z = counts[base + 2];
    }
    int s = v.x + v.y + v.z + v.w;
    ls[t] = s;
    __syncthreads();
    for (int o = 1; o < 256; o <<= 1) {
        int u = (t >= o) ? ls[t - o] : 0;
        __syncthreads();
        ls[t] += u;
        __syncthreads();
    }
    if (t == 255) bsum[blockIdx.x] = ls[255];
    int o0 = ls[t] - s;
    int o1 = o0 + v.x, o2 = o1 + v.y, o3 = o2 + v.z;
    if (base + 3 < n) { *(int4*)&offs[base] = make_int4(o0, o1, o2, o3); }
    else {
        if (base + 0 < n) offs[base + 0] = o0;
        if (base + 1 < n) offs[base + 1] = o1;
        if (base + 2 < n) offs[base + 2] = o2;
    }
}

__global__ __launch_bounds__(256) void k_scan2(int* __restrict__ bsum,
                                               int* __restrict__ offs, int nb,
                                               int total, int n) {
    __shared__ int ls[256];
    int t = threadIdx.x;
    int s = (t < nb) ? bsum[t] : 0;
    ls[t] = s;
    __syncthreads();
    for (int o = 1; o < 256; o <<= 1) {
        int u = (t >= o) ? ls[t - o] : 0;
        __syncthreads();
        ls[t] += u;
        __syncthreads();
    }
    if (t < nb) bsum[t] = ls[t] - s;      // exclusive block prefix
    if (t == 0) offs[n] = total;
}

__global__ __launch_bounds__(256) void k_scan3(int* __restrict__ offs,
                                               const int* __restrict__ bsum, int n) {
    int add = bsum[blockIdx.x];
    if (add == 0) return;
    int i = blockIdx.x * 1024 + threadIdx.x * 4;
    if (i + 3 < n) {
        int4 v = *(int4*)&offs[i];
        v.x += add; v.y += add; v.z += add; v.w += add;
        *(int4*)&offs[i] = v;
    } else {
        for (int j = 0; j < 4 && i + j < n; ++j) offs[i + j] += add;
    }
}

__global__ void k_scatter(const int* __restrict__ ei, const float* __restrict__ ea,
                          const float* __restrict__ easum, const int* __restrict__ offs,
                          int* __restrict__ cur, int* __restrict__ csrc,
                          float* __restrict__ cea, int E, int Nn) {
    float eam = easum[0] / (float)E;
    int total = E + Nn;
    for (int i = blockIdx.x * blockDim.x + threadIdx.x; i < total; i += gridDim.x * blockDim.x) {
        int s, d; float v;
        if (i < E) { s = ei[i]; d = ei[E + i]; v = ea[i]; }
        else       { s = d = i - E; v = eam; }
        int pos = offs[d] + atomicAdd(&cur[d], 1);
        csrc[pos] = s;
        cea[pos] = v;
    }
}

// ---------------- edge coefficient ----------------
__global__ __launch_bounds__(256) void k_coef(const float* __restrict__ we0, const float* __restrict__ ae0,
                                              const float* __restrict__ we1, const float* __restrict__ ae1,
                                              const float* __restrict__ we2, const float* __restrict__ ae2,
                                              float* __restrict__ coef) {
    int t = threadIdx.x, h = t >> 6, lane = t & 63;
    const float* we[3] = {we0, we1, we2};
    const float* ae[3] = {ae0, ae1, ae2};
#pragma unroll
    for (int l = 0; l < 3; ++l) {
        float p = we[l][t] * ae[l][t];
        p = warp64_sum(p);
        if (lane == 0) coef[l * 4 + h] = p;
    }
}

// ---------------- converters: fp32 -> fp16 ----------------
__global__ __launch_bounds__(256) void k_cvt_x(const float* __restrict__ x,
                                               _Float16* __restrict__ xh,
                                               int nvalid_rows, int cols, int total) {
    int i = blockIdx.x * 256 + threadIdx.x;
    if (i >= total) return;
    int r = i / cols;
    xh[i] = (r < nvalid_rows) ? (_Float16)x[i] : (_Float16)0.f;
}

// Wt[c*K + k] = W[k*256 + c]   (transposed fp16 weights)
__global__ __launch_bounds__(256) void k_cvt_w(const float* __restrict__ W,
                                               _Float16* __restrict__ Wt,
                                               int K, int total) {
    int i = blockIdx.x * 256 + threadIdx.x;
    if (i >= total) return;
    int c = i / K, k = i - c * K;
    Wt[i] = (_Float16)W[k * 256 + c];
}

// ---------------- MFMA GEMM: Out[N,256] = A[N,K] @ W[K,256]
// A fp16 [Npad,K]; Wt fp16 [256,K] (transposed); Out fp16; fused fp32 ssrc/sdst.
template <int KT>
__global__ __launch_bounds__(256) void k_gemm_mfma(const _Float16* __restrict__ A,
                                                   const _Float16* __restrict__ Wt,
                                                   _Float16* __restrict__ Out, int nrows,
                                                   const float* __restrict__ as_,
                                                   const float* __restrict__ ad_,
                                                   float* __restrict__ ssrc,
                                                   float* __restrict__ sdst) {
    const int tid = threadIdx.x;
    const int lane = tid & 63, wc = tid >> 6;
    const int l15 = lane & 15, g = lane >> 4;
    const int row0 = blockIdx.x * 64;

    f32x4 acc[4][4] = {};   // [m-frag][n-frag]

    const _Float16* Ab = A + (size_t)(row0 + l15) * KT + g * 8;
    const _Float16* Wb = Wt + (size_t)(wc * 64 + l15) * KT + g * 8;

#pragma unroll
    for (int kk = 0; kk < KT; kk += 32) {
        half8 af[4], bf[4];
#pragma unroll
        for (int m = 0; m < 4; ++m)
            af[m] = *(const half8*)(Ab + (size_t)m * 16 * KT + kk);
#pragma unroll
        for (int f = 0; f < 4; ++f)
            bf[f] = *(const half8*)(Wb + (size_t)f * 16 * KT + kk);
#pragma unroll
        for (int m = 0; m < 4; ++m)
#pragma unroll
            for (int f = 0; f < 4; ++f)
                acc[m][f] = __builtin_amdgcn_mfma_f32_16x16x32_f16(af[m], bf[f], acc[m][f], 0, 0, 0);
    }

    float asv[4], adv[4];
#pragma unroll
    for (int f = 0; f < 4; ++f) {
        asv[f] = as_[wc * 64 + f * 16 + l15];
        adv[f] = ad_[wc * 64 + f * 16 + l15];
    }

#pragma unroll
    for (int m = 0; m < 4; ++m) {
        float ps[4] = {}, pd[4] = {};
#pragma unroll
        for (int f = 0; f < 4; ++f)
#pragma unroll
            for (int j = 0; j < 4; ++j) {
                ps[j] = fmaf(acc[m][f][j], asv[f], ps[j]);
                pd[j] = fmaf(acc[m][f][j], adv[f], pd[j]);
            }
#pragma unroll
        for (int o = 1; o < 16; o <<= 1)
#pragma unroll
            for (int j = 0; j < 4; ++j) {
                ps[j] += __shfl_xor(ps[j], o, 64);
                pd[j] += __shfl_xor(pd[j], o, 64);
            }
        if (l15 == 0) {
#pragma unroll
            for (int j = 0; j < 4; ++j) {
                int r = row0 + m * 16 + g * 4 + j;
                if (r < nrows) {
                    ssrc[r * 4 + wc] = ps[j];
                    sdst[r * 4 + wc] = pd[j];
                }
            }
        }
#pragma unroll
        for (int f = 0; f < 4; ++f)
#pragma unroll
            for (int j = 0; j < 4; ++j) {
                int r = row0 + m * 16 + g * 4 + j;
                if (r < nrows)
                    Out[(size_t)r * 256 + wc * 64 + f * 16 + l15] = (_Float16)acc[m][f][j];
            }
    }
}

// ---------------- fused online-softmax aggregation: ONE NODE PER WAVE ----------------
template <bool MEAN>
__global__ __launch_bounds__(256) void k_agg(const _Float16* __restrict__ hlin,
                                             const int* __restrict__ offs,
                                             const int* __restrict__ csrc,
                                             const float* __restrict__ cea,
                                             const float* __restrict__ ssrc,
                                             const float* __restrict__ sdst,
                                             const float* __restrict__ coef,
                                             const float* __restrict__ bias,
                                             const float* __restrict__ bng,
                                             const float* __restrict__ bnb,
                                             const float* __restrict__ bnm,
                                             const float* __restrict__ bnv,
                                             _Float16* __restrict__ outh,
                                             float* __restrict__ outf, int Nn) {
    int n = blockIdx.x * 4 + (threadIdx.x >> 6);
    if (n >= Nn) return;
    int lane = threadIdx.x & 63;
    int h = lane >> 4;
    float sd = sdst[n * 4 + h], cf = coef[h];
    int b = offs[n], e = offs[n + 1];

    float m = -INFINITY, den = 0.f;
    float acc[4] = {};

    int sn = csrc[b];
    float ce = cea[b];
    half4 hv = *(const half4*)(hlin + (size_t)sn * 256 + lane * 4);
    float sv = ssrc[sn * 4 + h];
    for (int i = b; i < e; ++i) {
        int sn2 = 0; float ce2 = 0.f, sv2 = 0.f; half4 hv2 = {};
        if (i + 1 < e) {
            sn2 = csrc[i + 1];
            ce2 = cea[i + 1];
            hv2 = *(const half4*)(hlin + (size_t)sn2 * 256 + lane * 4);
            sv2 = ssrc[sn2 * 4 + h];
        }
        float a = sv + sd + cf * ce;
        a = a > 0.f ? a : 0.2f * a;                       // leaky_relu 0.2
        float mn = fmaxf(m, a);
        float sc = __expf(m - mn);
        float p = __expf(a - mn);
        den = den * sc + p;
#pragma unroll
        for (int j = 0; j < 4; ++j)
            acc[j] = acc[j] * sc + p * (float)hv[j];
        m = mn;
        sn = sn2; ce = ce2; hv = hv2; sv = sv2;
    }
    float inv = 1.f / den;

    if (!MEAN) {
        int c = lane * 4;
        float4 bi = *(const float4*)&bias[c];
        float4 g4 = *(const float4*)&bng[c];
        float4 b4 = *(const float4*)&bnb[c];
        float4 m4 = *(const float4*)&bnm[c];
        float4 v4 = *(const float4*)&bnv[c];
        half4 o;
#pragma unroll
        for (int j = 0; j < 4; ++j) {
            float v = acc[j] * inv + (&bi.x)[j];
            v = (v - (&m4.x)[j]) * rsqrtf((&v4.x)[j] + 1e-5f) * (&g4.x)[j] + (&b4.x)[j];
            v = v > 0.f ? v : expm1f(v);                  // ELU
            o[j] = (_Float16)v;
        }
        *(half4*)(outh + (size_t)n * 256 + c) = o;
    } else {
        float r[4];
#pragma unroll
        for (int j = 0; j < 4; ++j) {
            r[j] = acc[j] * inv;
            r[j] += __shfl_xor(r[j], 16, 64);
            r[j] += __shfl_xor(r[j], 32, 64);             // sum over 4 heads
        }
        if (lane < 16) {
            int c = lane * 4;
#pragma unroll
            for (int j = 0; j < 4; ++j) {
                float v = 0.25f * r[j] + bias[c + j];
                v = (v - bnm[c + j]) * rsqrtf(bnv[c + j] + 1e-5f) * bng[c + j] + bnb[c + j];
                outf[(size_t)n * 64 + c + j] = v;
            }
        }
    }
}

// ---------------- graph pooling: segmented (batch is sorted) ----------------
__global__ __launch_bounds__(256) void k_pool(const float* __restrict__ h2,
                                              const int* __restrict__ batch,
                                              float* __restrict__ psum,
                                              unsigned* __restrict__ pmaxk,
                                              float* __restrict__ pcnt, int Nn) {
    int wglob = blockIdx.x * 4 + (threadIdx.x >> 6);
    int lane = threadIdx.x & 63;
    int nwaves = gridDim.x * 4;
    int span = (Nn + nwaves - 1) / nwaves;
    int b = wglob * span, e = min(b + span, Nn);
    if (b >= e) return;
    int curg = batch[b];
    float s = 0.f, mx = -INFINITY;
    float cnt = 0.f;
    for (int i = b; i < e; ++i) {
        int g = batch[i];
        float v = h2[(size_t)i * 64 + lane];
        if (g != curg) {
            atomicAdd(&psum[curg * 64 + lane], s);
            atomicMax(&pmaxk[curg * 64 + lane], fkey(mx));
            if (lane == 0) atomicAdd(&pcnt[curg], cnt);
            s = 0.f; mx = -INFINITY; cnt = 0.f; curg = g;
        }
        s += v; mx = fmaxf(mx, v); cnt += 1.f;
    }
    atomicAdd(&psum[curg * 64 + lane], s);
    atomicMax(&pmaxk[curg * 64 + lane], fkey(mx));
    if (lane == 0) atomicAdd(&pcnt[curg], cnt);
}

// ---------------- MLP head ----------------
__global__ __launch_bounds__(128) void k_mlp(const float* __restrict__ psum,
                                             const unsigned* __restrict__ pmaxk,
                                             const float* __restrict__ pcnt,
                                             const float* __restrict__ emb,
                                             const int* __restrict__ cids,
                                             const float* __restrict__ mw1, const float* __restrict__ mb1,
                                             const float* __restrict__ mw2, const float* __restrict__ mb2,
                                             const float* __restrict__ mw3, const float* __restrict__ mb3,
                                             float* __restrict__ out) {
    __shared__ float comb[144];
    __shared__ float z1[128];
    __shared__ float z2[64];
    int g = blockIdx.x, t = threadIdx.x;
    float cnt = fmaxf(pcnt[g], 1.f);
    if (t < 64) {
        comb[t] = psum[g * 64 + t] / cnt;
        comb[64 + t] = fdecode(pmaxk[g * 64 + t]);
    }
    if (t < 16) comb[128 + t] = emb[cids[g] * 16 + t];
    __syncthreads();
    float a = mb1[t];
    for (int k = 0; k < 144; ++k) a = fmaf(comb[k], mw1[k * 128 + t], a);
    z1[t] = fmaxf(a, 0.f);
    __syncthreads();
    if (t < 64) {
        float a2 = mb2[t];
        for (int k = 0; k < 128; ++k) a2 = fmaf(z1[k], mw2[k * 64 + t], a2);
        z2[t] = fmaxf(a2, 0.f);
    }
    __syncthreads();
    if (t < 2) {
        float a3 = mb3[t];
        for (int k = 0; k < 64; ++k) a3 = fmaf(z2[k], mw3[k * 2 + t], a3);
        out[g * 2 + t] = a3;
    }
}

extern "C" void kernel_launch(void* const* d_in, const int* in_sizes, int n_in,
                              void* d_out, int out_size, void* d_ws, size_t ws_size,
                              hipStream_t stream) {
    const float* x         = (const float*)d_in[0];
    const float* edge_attr = (const float*)d_in[1];
    const float* w0  = (const float*)d_in[2];
    const float* as0 = (const float*)d_in[3];
    const float* ad0 = (const float*)d_in[4];
    const float* we0 = (const float*)d_in[5];
    const float* ae0 = (const float*)d_in[6];
    const float* w1  = (const float*)d_in[7];
    const float* as1 = (const float*)d_in[8];
    const float* ad1 = (const float*)d_in[9];
    const float* we1 = (const float*)d_in[10];
    const float* ae1 = (const float*)d_in[11];
    const float* w2  = (const float*)d_in[12];
    const float* as2 = (const float*)d_in[13];
    const float* ad2 = (const float*)d_in[14];
    const float* we2 = (const float*)d_in[15];
    const float* ae2 = (const float*)d_in[16];
    const float* b0  = (const float*)d_in[17];
    const float* b1  = (const float*)d_in[18];
    const float* b2  = (const float*)d_in[19];
    const float* bn_g0 = (const float*)d_in[20];
    const float* bn_b0 = (const float*)d_in[21];
    const float* bn_m0 = (const float*)d_in[22];
    const float* bn_v0 = (const float*)d_in[23];
    const float* bn_g1 = (const float*)d_in[24];
    const float* bn_b1 = (const float*)d_in[25];
    const float* bn_m1 = (const float*)d_in[26];
    const float* bn_v1 = (const float*)d_in[27];
    const float* bn_g2 = (const float*)d_in[28];
    const float* bn_b2 = (const float*)d_in[29];
    const float* bn_m2 = (const float*)d_in[30];
    const float* bn_v2 = (const float*)d_in[31];
    const float* emb = (const float*)d_in[32];
    const float* mw1 = (const float*)d_in[33];
    const float* mb1 = (const float*)d_in[34];
    const float* mw2 = (const float*)d_in[35];
    const float* mb2 = (const float*)d_in[36];
    const float* mw3 = (const float*)d_in[37];
    const float* mb3 = (const float*)d_in[38];
    const int* edge_index = (const int*)d_in[39];
    const int* batch      = (const int*)d_in[40];
    const int* cids       = (const int*)d_in[41];

    const int N = in_sizes[40];       // 50000
    const int E = in_sizes[1];        // 300000
    const int G = in_sizes[41];       // 128
    const int EP = E + N;
    const int NB = (N + 63) / 64;     // gemm blocks
    const int Npad = NB * 64;         // padded rows
    const int NSB = (N + 1023) / 1024; // scan blocks (<=256)

    // ---- workspace layout ----
    size_t off = 0;
    auto alloc = [&](size_t bytes) -> void* {
        void* p = (char*)d_ws + off;
        off += (bytes + 255) & ~(size_t)255;
        return p;
    };
    // zero-init prefix
    int*      counts = (int*)alloc((size_t)N * 4);
    int*      cursor = (int*)alloc((size_t)N * 4);
    float*    psum   = (float*)alloc((size_t)G * 64 * 4);
    unsigned* pmaxk  = (unsigned*)alloc((size_t)G * 64 * 4);
    float*    pcnt   = (float*)alloc((size_t)G * 4);
    float*    easum  = (float*)alloc(4);
    size_t zbytes = off;
    // rest
    int*   offs = (int*)alloc((size_t)(N + 1) * 4);
    int*   bsum = (int*)alloc(256 * 4);
    int*   csrc = (int*)alloc((size_t)EP * 4);
    float* cea  = (float*)alloc((size_t)EP * 4);
    float* ssrc = (float*)alloc((size_t)N * 4 * 4);
    float* sdst = (float*)alloc((size_t)N * 4 * 4);
    float* coef = (float*)alloc(12 * 4);
    _Float16* xh  = (_Float16*)alloc((size_t)Npad * 32 * 2);
    _Float16* wt0 = (_Float16*)alloc((size_t)256 * 32 * 2);
    _Float16* wt1 = (_Float16*)alloc((size_t)256 * 256 * 2);
    _Float16* wt2 = (_Float16*)alloc((size_t)256 * 256 * 2);
    _Float16* hH  = (_Float16*)alloc((size_t)Npad * 256 * 2);  // GEMM out (fp16, gather src)
    _Float16* hB  = (_Float16*)alloc((size_t)Npad * 256 * 2);  // agg out (fp16, GEMM in)
    float*    h2  = (float*)alloc((size_t)N * 64 * 4);         // layer-2 out
    (void)ws_size; (void)n_in; (void)out_size;

    hipMemsetAsync(d_ws, 0, zbytes, stream);

    // ---- graph preprocessing ----
    k_easum<<<512, 256, 0, stream>>>(edge_attr, easum, E);
    k_count<<<1024, 256, 0, stream>>>(edge_index, counts, E, N);
    k_scan1<<<NSB, 256, 0, stream>>>(counts, offs, bsum, N);
    k_scan2<<<1, 256, 0, stream>>>(bsum, offs, NSB, EP, N);
    k_scan3<<<NSB, 256, 0, stream>>>(offs, bsum, N);
    k_scatter<<<1024, 256, 0, stream>>>(edge_index, edge_attr, easum, offs, cursor, csrc, cea, E, N);
    k_coef<<<1, 256, 0, stream>>>(we0, ae0, we1, ae1, we2, ae2, coef);

    // ---- fp16 conversions ----
    {
        int tot = Npad * 32;
        k_cvt_x<<<(tot + 255) / 256, 256, 0, stream>>>(x, xh, N, 32, tot);
        k_cvt_w<<<(256 * 32 + 255) / 256, 256, 0, stream>>>(w0, wt0, 32, 256 * 32);
        k_cvt_w<<<(256 * 256 + 255) / 256, 256, 0, stream>>>(w1, wt1, 256, 256 * 256);
        k_cvt_w<<<(256 * 256 + 255) / 256, 256, 0, stream>>>(w2, wt2, 256, 256 * 256);
    }

    int agg_grid = (N + 3) / 4;

    // ---- layer 0 ----
    k_gemm_mfma<32><<<NB, 256, 0, stream>>>(xh, wt0, hH, N, as0, ad0, ssrc, sdst);
    k_agg<false><<<agg_grid, 256, 0, stream>>>(hH, offs, csrc, cea, ssrc, sdst, coef + 0,
                                               b0, bn_g0, bn_b0, bn_m0, bn_v0, hB, nullptr, N);
    // ---- layer 1 ----
    k_gemm_mfma<256><<<NB, 256, 0, stream>>>(hB, wt1, hH, N, as1, ad1, ssrc, sdst);
    k_agg<false><<<agg_grid, 256, 0, stream>>>(hH, offs, csrc, cea, ssrc, sdst, coef + 4,
                                               b1, bn_g1, bn_b1, bn_m1, bn_v1, hB, nullptr, N);
    // ---- layer 2 ----
    k_gemm_mfma<256><<<NB, 256, 0, stream>>>(hB, wt2, hH, N, as2, ad2, ssrc, sdst);
    k_agg<true><<<agg_grid, 256, 0, stream>>>(hH, offs, csrc, cea, ssrc, sdst, coef + 8,
                                              b2, bn_g2, bn_b2, bn_m2, bn_v2, nullptr, h2, N);

    // ---- pooling + MLP head ----
    k_pool<<<512, 256, 0, stream>>>(h2, batch, psum, pmaxk, pcnt, N);
    k_mlp<<<G, 128, 0, stream>>>(psum, pmaxk, pcnt, emb, cids,
                                 mw1, mb1, mw2, mb2, mw3, mb3, (float*)d_out);
}